// Round 5
// baseline (874.265 us; speedup 1.0000x reference)
//
#include <hip/hip_runtime.h>
#include <hip/hip_bf16.h>

#define N_NODES 50000
#define N_EDGES 500000
#define DIM 128

typedef __bf16 bf16_t;
typedef __bf16 bf16x8 __attribute__((ext_vector_type(8)));
typedef __bf16 bf16x2 __attribute__((ext_vector_type(2)));
typedef float f32x4 __attribute__((ext_vector_type(4)));

#define MFMA(a,b,c) __builtin_amdgcn_mfma_f32_16x16x32_bf16((a),(b),(c),0,0,0)

// XOR swizzle (guide G4): kills 32-way bank conflicts for 256B/512B-stride rows
__device__ __forceinline__ int swz(int row, int kbyte){ return kbyte ^ ((row & 7) << 4); }
// full 4-bit row swizzle for the h buffer (256B rows, 16-row period)
__device__ __forceinline__ int hswz(int row, int kbyte){ return kbyte ^ ((row & 15) << 4); }

__device__ __forceinline__ bf16x8 lds_frag(const char* s, int row, int rowb, int kbyte){
  return *(const bf16x8*)(s + row * rowb + swz(row, kbyte));
}

__device__ __forceinline__ void copy16(char* dst, const char* __restrict__ src, int bytes){
  for (int o = threadIdx.x * 16; o < bytes; o += blockDim.x * 16)
    *(f32x4*)(dst + o) = *(const f32x4*)(src + o);
}

// ---------------- weight prep: f32 [K][N] -> bf16 transposed swizzled image [n][k] ----------------
// mode 1: permute output-col n -> ((n&7)<<4)|(n>>3)   (thread's 8 C elems = contiguous logical cols)
// mode 3: permute output-col n -> ((n&15)<<4)|(n>>4)  (W1, N=256: 16 contiguous logical hcols/thread)
struct WPrep {
  const float* w[10];
  int Kd[10], Nd[10], off[10], cum[10], mode[10];
};

__global__ void k_wprep(WPrep d, char* img, int total){
  for (int idx = blockIdx.x * blockDim.x + threadIdx.x; idx < total; idx += gridDim.x * blockDim.x){
    int i = 0;
#pragma unroll
    for (int j = 1; j < 10; j++) if (idx >= d.cum[j]) i = j;
    int loc = idx - d.cum[i];
    int K = d.Kd[i], N = d.Nd[i];
    int n = loc / K, k = loc - n * K;
    float val = d.w[i][(size_t)k * N + n];
    int nn = n;
    if (d.mode[i] == 1) nn = ((n & 7) << 4) | (n >> 3);
    if (d.mode[i] == 3) nn = ((n & 15) << 4) | (n >> 4);
    *(bf16_t*)(img + d.off[i] + nn * (K * 2) + swz(nn, k * 2)) = (bf16_t)val;
  }
}

// ---------------- CSR build ----------------
__global__ void k_count(const int* __restrict__ dst, int* __restrict__ cnt){
  int i = blockIdx.x * blockDim.x + threadIdx.x;
  if (i < N_EDGES) atomicAdd(&cnt[dst[i]], 1);
}

__global__ __launch_bounds__(1024) void k_scan(const int* __restrict__ cnt,
                                               int* __restrict__ rowptr, int* __restrict__ wp){
  __shared__ int wsum[16];
  __shared__ int wpre[16];
  __shared__ int scarry;
  const int tid = threadIdx.x, lane = tid & 63, wv = tid >> 6;
  if (tid == 0) scarry = 0;
  for (int base = 0; base < N_NODES; base += 8192){
    int i0 = base + tid * 8;
    int v[8], p[8];
    int tsum = 0;
#pragma unroll
    for (int j = 0; j < 8; j++){
      int idx = i0 + j;
      v[j] = (idx < N_NODES) ? cnt[idx] : 0;
      p[j] = tsum; tsum += v[j];
    }
    int x = tsum;
#pragma unroll
    for (int off = 1; off < 64; off <<= 1){
      int t = __shfl_up(x, off);
      if (lane >= off) x += t;
    }
    if (lane == 63) wsum[wv] = x;
    __syncthreads();
    if (tid == 0){
      int run = scarry;
#pragma unroll
      for (int j = 0; j < 16; j++){ int t = wsum[j]; wpre[j] = run; run += t; }
      scarry = run;
    }
    __syncthreads();
    int texcl = wpre[wv] + x - tsum;
#pragma unroll
    for (int j = 0; j < 8; j++){
      int idx = i0 + j;
      if (idx < N_NODES){ rowptr[idx] = texcl + p[j]; wp[idx] = texcl + p[j]; }
    }
  }
  __syncthreads();
  if (tid == 0) rowptr[N_NODES] = scarry;
}

__global__ void k_fill(const int* __restrict__ dst, int* __restrict__ wp, int* __restrict__ csr){
  int i = blockIdx.x * blockDim.x + threadIdx.x;
  if (i < N_EDGES){
    int p = atomicAdd(&wp[dst[i]], 1);
    csr[p] = i;
  }
}

// ---------------- QKV: [M,128] @ 3x [128,128] -> bf16 outputs (mode-1 weights -> vector stores) ----------------
__global__ __launch_bounds__(512) void k_qkv(
    const float* __restrict__ v, const char* __restrict__ img,
    bf16_t* __restrict__ Q, bf16_t* __restrict__ K, bf16_t* __restrict__ V, int M)
{
  __shared__ __align__(16) char sm[65536];
  char* sX = sm;
  char* sW = sm + 32768;
  const int tid = threadIdx.x, lane = tid & 63, wave = tid >> 6;
  const int r0 = blockIdx.x * 128;
  for (int c = tid; c < 2048; c += 512){
    int row = c >> 4, kc = c & 15, grow = r0 + row;
    float f[8];
    if (grow < M){
      const float4* p = (const float4*)(v + (size_t)grow * DIM + kc * 8);
      float4 u0 = p[0], u1 = p[1];
      f[0]=u0.x; f[1]=u0.y; f[2]=u0.z; f[3]=u0.w;
      f[4]=u1.x; f[5]=u1.y; f[6]=u1.z; f[7]=u1.w;
    } else {
#pragma unroll
      for (int j=0;j<8;j++) f[j] = 0.f;
    }
    bf16x8 o;
#pragma unroll
    for (int j=0;j<8;j++) o[j] = (bf16_t)f[j];
    *(bf16x8*)(sX + row * 256 + swz(row, kc * 16)) = o;
  }
  const int rowA = wave * 16 + (lane & 15);
  const int kb0 = (lane >> 4) * 16;
  const int crow = wave*16 + (lane >> 4)*4;
  const int ccol = lane & 15;
  const f32x4 zero4 = {0.f, 0.f, 0.f, 0.f};
#pragma unroll
  for (int w3 = 0; w3 < 3; w3++){
    __syncthreads();            // staging done / prev GEMM done with sW
    copy16(sW, img + w3 * 32768, 32768);
    __syncthreads();
    f32x4 acc[8];
#pragma unroll
    for (int b=0;b<8;b++) acc[b] = zero4;
#pragma unroll
    for (int ks=0; ks<4; ks++){
      bf16x8 a = lds_frag(sX, rowA, 256, ks*64 + kb0);
#pragma unroll
      for (int nt=0; nt<8; nt++){
        int rn = nt*16 + (lane & 15);
        bf16x8 b = lds_frag(sW, rn, 256, ks*64 + kb0);
        acc[nt] = MFMA(a, b, acc[nt]);
      }
    }
    bf16_t* o = (w3 == 0) ? Q : ((w3 == 1) ? K : V);
    // mode-1 perm: acc[nt] = logical col ccol*8+nt -> one bf16x8 store per row
#pragma unroll
    for (int r=0; r<4; r++){
      int grow = r0 + crow + r;
      if (grow < M){
        bf16x8 t;
#pragma unroll
        for (int nt=0; nt<8; nt++) t[nt] = (bf16_t)acc[nt][r];
        *(bf16x8*)(o + (size_t)grow * DIM + ccol*8) = t;
      }
    }
  }
}

// ---------------- fused edge attention ----------------
// We/WO_e both mode-1 col-permuted: C elem (nt,ccol) = logical col ccol*8+nt.
// Score written to LDS at LOGICAL positions (one bf16x8/row) -> WO_e needs no k-perm.
__global__ __launch_bounds__(512, 4) void k_edge(
    const float* __restrict__ e,
    const int* __restrict__ src, const int* __restrict__ dst,
    const bf16_t* __restrict__ Qb, const bf16_t* __restrict__ Kb,
    const char* __restrict__ imgWe, const char* __restrict__ imgWo,
    const float* __restrict__ bOe,
    float* __restrict__ e1_pre, float* __restrict__ sv,
    float* __restrict__ stats, int M)
{
  __shared__ __align__(16) char sm[66560];
  char* sW = sm;                          // 32KB: We then WO_e
  char* sX = sm + 32768;                  // 32KB: e tile, then score
  float* sStats = (float*)(sm + 65536);   // 256 f
  const int tid = threadIdx.x, lane = tid & 63, wave = tid >> 6;
  const int r0 = blockIdx.x * 128;
  const int crow = wave*16 + (lane >> 4)*4;
  const int ccol = lane & 15;
  // prefetch K[src]/Q[dst] fragments (in flight through staging + GEMM1)
  bf16x8 Kg[4], Qg[4];
#pragma unroll
  for (int r=0;r<4;r++){
    int ed = r0 + crow + r; if (ed >= M) ed = M - 1;
    int sn = src[ed], dn = dst[ed];
    Kg[r] = *(const bf16x8*)(Kb + (size_t)sn * DIM + ccol * 8);
    Qg[r] = *(const bf16x8*)(Qb + (size_t)dn * DIM + ccol * 8);
  }
  copy16(sW, imgWe, 32768);
  if (tid < 256) sStats[tid] = 0.f;
  for (int c = tid; c < 2048; c += 512){
    int row = c >> 4, kc = c & 15, grow = r0 + row;
    float f[8];
    if (grow < M){
      const float4* p = (const float4*)(e + (size_t)grow * DIM + kc * 8);
      float4 u0 = p[0], u1 = p[1];
      f[0]=u0.x; f[1]=u0.y; f[2]=u0.z; f[3]=u0.w;
      f[4]=u1.x; f[5]=u1.y; f[6]=u1.z; f[7]=u1.w;
    } else {
#pragma unroll
      for (int j=0;j<8;j++) f[j] = 0.f;
    }
    bf16x8 o;
#pragma unroll
    for (int j=0;j<8;j++) o[j] = (bf16_t)f[j];
    *(bf16x8*)(sX + row * 256 + swz(row, kc * 16)) = o;
  }
  __syncthreads();
  const int rowA = wave * 16 + (lane & 15);
  const int kb0 = (lane >> 4) * 16;
  const f32x4 zero4 = {0.f,0.f,0.f,0.f};
  f32x4 pe[8];
#pragma unroll
  for (int i=0;i<8;i++) pe[i] = zero4;
#pragma unroll
  for (int ks=0; ks<4; ks++){
    bf16x8 a = lds_frag(sX, rowA, 256, ks*64 + kb0);
#pragma unroll
    for (int nt=0; nt<8; nt++){
      int rn = nt*16 + (lane & 15);
      bf16x8 b = lds_frag(sW, rn, 256, ks*64 + kb0);
      pe[nt] = MFMA(a, b, pe[nt]);
    }
  }
  __syncthreads();   // done reading sX (e tile) and sW (We)
  copy16(sW, imgWo, 32768);               // WO_e into the same buffer (overlaps score phase)
  // score: logical col ccol*8+nt -> one bf16x8 per row (logical LDS layout)
#pragma unroll
  for (int r=0;r<4;r++){
    int row = crow + r;
    bf16x8 t;
    float hsum = 0.f;
#pragma unroll
    for (int nt=0; nt<8; nt++){
      float sc = pe[nt][r] * 0.25f * (float)Kg[r][nt] * (float)Qg[r][nt];
      t[nt] = (bf16_t)sc;
      hsum += sc;
    }
    *(bf16x8*)(sX + row*256 + swz(row, ccol*16)) = t;
    float ts = hsum + __shfl_xor(hsum, 1);   // pair covers the full 16-col head
    int ed = r0 + row;
    if (!(ccol & 1) && ed < M)
      sv[(size_t)ed*8 + (ccol >> 1)] = __expf(fminf(5.f, fmaxf(-5.f, ts)));
  }
  __syncthreads();
  // GEMM2: e_attn @ WO_e (score logical layout, WO_e mode-1)
  f32x4 a2[8];
#pragma unroll
  for (int i=0;i<8;i++) a2[i] = zero4;
#pragma unroll
  for (int ks=0; ks<4; ks++){
    bf16x8 a = lds_frag(sX, rowA, 256, ks*64 + kb0);
#pragma unroll
    for (int nt=0; nt<8; nt++){
      int rn = nt*16 + (lane & 15);
      bf16x8 b = lds_frag(sW, rn, 256, ks*64 + kb0);
      a2[nt] = MFMA(a, b, a2[nt]);
    }
  }
  // epilogue: vectorized (logical cols ccol*8..+7)
  float4 bo0 = *(const float4*)(bOe + ccol*8);
  float4 bo1 = *(const float4*)(bOe + ccol*8 + 4);
  float s1[8], s2[8];
#pragma unroll
  for (int j=0;j<8;j++){ s1[j]=0.f; s2[j]=0.f; }
#pragma unroll
  for (int r=0; r<4; r++){
    int ed = r0 + crow + r;
    float val[8];
    if (ed < M){
      const float4* ep = (const float4*)(e + (size_t)ed*DIM + ccol*8);
      float4 e0 = ep[0], e1v = ep[1];
      val[0]=a2[0][r]+e0.x +bo0.x; val[1]=a2[1][r]+e0.y +bo0.y;
      val[2]=a2[2][r]+e0.z +bo0.z; val[3]=a2[3][r]+e0.w +bo0.w;
      val[4]=a2[4][r]+e1v.x+bo1.x; val[5]=a2[5][r]+e1v.y+bo1.y;
      val[6]=a2[6][r]+e1v.z+bo1.z; val[7]=a2[7][r]+e1v.w+bo1.w;
      float4 o0 = {val[0],val[1],val[2],val[3]};
      float4 o1 = {val[4],val[5],val[6],val[7]};
      float4* op = (float4*)(e1_pre + (size_t)ed*DIM + ccol*8);
      op[0] = o0; op[1] = o1;
    } else {
#pragma unroll
      for (int j=0;j<8;j++) val[j]=0.f;
    }
#pragma unroll
    for (int j=0;j<8;j++){ s1[j] += val[j]; s2[j] += val[j]*val[j]; }
  }
#pragma unroll
  for (int j=0;j<8;j++){
    s1[j] += __shfl_xor(s1[j], 16); s1[j] += __shfl_xor(s1[j], 32);
    s2[j] += __shfl_xor(s2[j], 16); s2[j] += __shfl_xor(s2[j], 32);
  }
  if (lane < 16){
#pragma unroll
    for (int j=0;j<8;j++){
      atomicAdd(&sStats[ccol*8 + j], s1[j]);
      atomicAdd(&sStats[128 + ccol*8 + j], s2[j]);
    }
  }
  __syncthreads();
  if (tid < 256) unsafeAtomicAdd(&stats[tid], sStats[tid]);
}

// ---------------- aggregation: one wave per node, CSR walk, no atomics ----------------
__global__ __launch_bounds__(512) void k_agg(
    const int* __restrict__ rowptr, const int* __restrict__ csr,
    const int* __restrict__ src, const float* __restrict__ envl,
    const float* __restrict__ sv, const bf16_t* __restrict__ V,
    bf16_t* __restrict__ vAttn, int M)
{
  const int wave = threadIdx.x >> 6, lane = threadIdx.x & 63;
  const int n = blockIdx.x * 8 + wave;
  if (n >= M) return;
  const int beg = rowptr[n], end = rowptr[n + 1];
  const int h = lane >> 3;           // head of cols (2*lane, 2*lane+1)
  float ax = 0.f, ay = 0.f, zacc = 0.f;
  for (int i = beg; i < end; i++){
    int eid = csr[i];
    int sn = src[eid];
    float s = sv[(size_t)eid * 8 + h];
    float env = envl[eid];
    const bf16x2 vv = *(const bf16x2*)(V + (size_t)sn * DIM + lane * 2);
    float w = env * s;
    ax += (float)vv[0] * w; ay += (float)vv[1] * w;
    zacc += s;
  }
  float inv = 1.f / (zacc + 1e-6f);
  bf16x2 o; o[0] = (bf16_t)(ax * inv); o[1] = (bf16_t)(ay * inv);
  *(bf16x2*)(vAttn + (size_t)n * DIM + lane * 2) = o;
}

// ---------------- node: v1_pre = v + v_attn@WO_v + bOv; stats (WO_v mode-1) ----------------
__global__ __launch_bounds__(512) void k_nodeout(
    const bf16_t* __restrict__ vAttn, const float* __restrict__ v,
    const char* __restrict__ imgWo, const float* __restrict__ bOv,
    float* __restrict__ v1_pre, float* __restrict__ stats, int M)
{
  __shared__ __align__(16) char sm[66560];
  char* sW = sm;
  char* sX = sm + 32768;
  float* sStats = (float*)(sm + 65536);
  const int tid = threadIdx.x, lane = tid & 63, wave = tid >> 6;
  const int r0 = blockIdx.x * 128;
  copy16(sW, imgWo, 32768);
  if (tid < 256) sStats[tid] = 0.f;
  for (int c = tid; c < 2048; c += 512){
    int row = c >> 4, kc = c & 15, grow = r0 + row;
    bf16x8 o;
    if (grow < M){
      o = *(const bf16x8*)(vAttn + (size_t)grow * DIM + kc * 8);
    } else {
#pragma unroll
      for (int j=0;j<8;j++) o[j] = (bf16_t)0.f;
    }
    *(bf16x8*)(sX + row*256 + swz(row, kc*16)) = o;
  }
  __syncthreads();
  const int rowA = wave*16 + (lane & 15);
  const int kb0 = (lane >> 4)*16;
  const f32x4 zero4 = {0.f,0.f,0.f,0.f};
  f32x4 acc[8];
#pragma unroll
  for (int i=0;i<8;i++) acc[i]=zero4;
#pragma unroll
  for (int ks=0;ks<4;ks++){
    bf16x8 a = lds_frag(sX, rowA, 256, ks*64+kb0);
#pragma unroll
    for (int nt=0;nt<8;nt++){
      int rn = nt*16 + (lane&15);
      bf16x8 b = lds_frag(sW, rn, 256, ks*64+kb0);
      acc[nt] = MFMA(a,b,acc[nt]);
    }
  }
  const int crow = wave*16 + (lane>>4)*4;
  const int ccol = lane & 15;
  float4 bo0 = *(const float4*)(bOv + ccol*8);
  float4 bo1 = *(const float4*)(bOv + ccol*8 + 4);
  float s1[8], s2[8];
#pragma unroll
  for (int j=0;j<8;j++){ s1[j]=0.f; s2[j]=0.f; }
#pragma unroll
  for (int r=0;r<4;r++){
    int grow = r0 + crow + r;
    float val[8];
    if (grow < M){
      const float4* vp = (const float4*)(v + (size_t)grow*DIM + ccol*8);
      float4 v0 = vp[0], v1 = vp[1];
      val[0]=acc[0][r]+v0.x+bo0.x; val[1]=acc[1][r]+v0.y+bo0.y;
      val[2]=acc[2][r]+v0.z+bo0.z; val[3]=acc[3][r]+v0.w+bo0.w;
      val[4]=acc[4][r]+v1.x+bo1.x; val[5]=acc[5][r]+v1.y+bo1.y;
      val[6]=acc[6][r]+v1.z+bo1.z; val[7]=acc[7][r]+v1.w+bo1.w;
      float4 o0 = {val[0],val[1],val[2],val[3]};
      float4 o1 = {val[4],val[5],val[6],val[7]};
      float4* op = (float4*)(v1_pre + (size_t)grow*DIM + ccol*8);
      op[0] = o0; op[1] = o1;
    } else {
#pragma unroll
      for (int j=0;j<8;j++) val[j]=0.f;
    }
#pragma unroll
    for (int j=0;j<8;j++){ s1[j] += val[j]; s2[j] += val[j]*val[j]; }
  }
#pragma unroll
  for (int j=0;j<8;j++){
    s1[j] += __shfl_xor(s1[j], 16); s1[j] += __shfl_xor(s1[j], 32);
    s2[j] += __shfl_xor(s2[j], 16); s2[j] += __shfl_xor(s2[j], 32);
  }
  if (lane < 16){
#pragma unroll
    for (int j=0;j<8;j++){
      atomicAdd(&sStats[ccol*8 + j], s1[j]);
      atomicAdd(&sStats[128 + ccol*8 + j], s2[j]);
    }
  }
  __syncthreads();
  if (tid < 256) unsafeAtomicAdd(&stats[tid], sStats[tid]);
}

// ---------------- fused FFN ----------------
// W1 mode-3 (16 contiguous logical hcols/thread, h in bf16 VGPRs); W2 mode-1 (vector epilogue).
// Staging uses the epilogue footprint (rows crow..+3, cols ccol*8..+7) -> per-thread ss constants.
__global__ __launch_bounds__(512, 4) void k_ffn(
    float* __restrict__ xio, const float* __restrict__ ss1,
    const char* __restrict__ img1, const float* __restrict__ b1,
    const char* __restrict__ img2, const float* __restrict__ b2,
    float* __restrict__ stats2, int M)
{
  __shared__ __align__(16) char sm[66560];
  char* sA = sm;           // x1 tile (bf16); later h halves (hswz layout)
  char* sB = sm + 32768;   // W1h0, W1h1, W2k0, W2k1
  float* sStats = (float*)(sm + 65536);
  const int tid = threadIdx.x, lane = tid & 63, wave = tid >> 6;
  const int r0 = blockIdx.x * 128;
  const int rowA = wave*16 + (lane & 15);
  const int kb0 = (lane >> 4) * 16;
  const int crow = wave*16 + (lane >> 4)*4;
  const int ccol = lane & 15;
  const f32x4 zero4 = {0.f,0.f,0.f,0.f};

  // BN scale/shift for this thread's 8 contiguous cols
  float4 sc0 = *(const float4*)(ss1 + ccol*8);
  float4 sc1 = *(const float4*)(ss1 + ccol*8 + 4);
  float4 sh0 = *(const float4*)(ss1 + 128 + ccol*8);
  float4 sh1 = *(const float4*)(ss1 + 128 + ccol*8 + 4);
  // biases for this thread's 16 contiguous logical hcols
  const float4* bq = (const float4*)(b1 + ccol * 16);
  float4 bq0 = bq[0], bq1 = bq[1], bq2 = bq[2], bq3 = bq[3];

  // phase 1: stage x1 tile (epilogue footprint) + W1 half0
  copy16(sB, img1, 32768);
  if (tid < 256) sStats[tid] = 0.f;
#pragma unroll
  for (int r = 0; r < 4; r++){
    int row = crow + r, grow = r0 + row;
    bf16x8 o;
    if (grow < M){
      const float4* p = (const float4*)(xio + (size_t)grow*DIM + ccol*8);
      float4 u0 = p[0], u1 = p[1];
      o[0]=(bf16_t)(u0.x*sc0.x+sh0.x); o[1]=(bf16_t)(u0.y*sc0.y+sh0.y);
      o[2]=(bf16_t)(u0.z*sc0.z+sh0.z); o[3]=(bf16_t)(u0.w*sc0.w+sh0.w);
      o[4]=(bf16_t)(u1.x*sc1.x+sh1.x); o[5]=(bf16_t)(u1.y*sc1.y+sh1.y);
      o[6]=(bf16_t)(u1.z*sc1.z+sh1.z); o[7]=(bf16_t)(u1.w*sc1.w+sh1.w);
    } else {
#pragma unroll
      for (int j=0;j<8;j++) o[j]=(bf16_t)0.f;
    }
    *(bf16x8*)(sA + row*256 + swz(row, ccol*16)) = o;
  }
  __syncthreads();

  bf16x8 hreg[8];   // [r] = half0 hcols (nt 0..7), [4+r] = half1 (nt 8..15)
  f32x4 wbuf[4];    // reg-staged next weight chunk

  // phase 2: GEMM1a (+ issue W1 half1 loads)
#pragma unroll
  for (int i=0;i<4;i++) wbuf[i] = *(const f32x4*)(img1 + 32768 + tid*16 + i*8192);
  {
    f32x4 acc[8];
#pragma unroll
    for (int i=0;i<8;i++) acc[i]=zero4;
#pragma unroll
    for (int ks=0;ks<4;ks++){
      bf16x8 a = lds_frag(sA, rowA, 256, ks*64+kb0);
#pragma unroll
      for (int nt=0;nt<8;nt++){
        int rn = nt*16 + (lane&15);
        bf16x8 b = lds_frag(sB, rn, 256, ks*64+kb0);
        acc[nt] = MFMA(a,b,acc[nt]);
      }
    }
#pragma unroll
    for (int r=0;r<4;r++){
      bf16x8 t;
      t[0]=(bf16_t)fmaxf(acc[0][r]+bq0.x,0.f); t[1]=(bf16_t)fmaxf(acc[1][r]+bq0.y,0.f);
      t[2]=(bf16_t)fmaxf(acc[2][r]+bq0.z,0.f); t[3]=(bf16_t)fmaxf(acc[3][r]+bq0.w,0.f);
      t[4]=(bf16_t)fmaxf(acc[4][r]+bq1.x,0.f); t[5]=(bf16_t)fmaxf(acc[5][r]+bq1.y,0.f);
      t[6]=(bf16_t)fmaxf(acc[6][r]+bq1.z,0.f); t[7]=(bf16_t)fmaxf(acc[7][r]+bq1.w,0.f);
      hreg[r] = t;
    }
  }
  __syncthreads();
  // phase 3: write W1 half1
#pragma unroll
  for (int i=0;i<4;i++) *(f32x4*)(sB + tid*16 + i*8192) = wbuf[i];
  __syncthreads();
  // phase 4: GEMM1b (+ issue W2 k-half0 loads)
#pragma unroll
  for (int i=0;i<4;i++){
    int o = tid*16 + i*8192;
    wbuf[i] = *(const f32x4*)(img2 + (o >> 8)*512 + (o & 255));
  }
  {
    f32x4 acc[8];
#pragma unroll
    for (int i=0;i<8;i++) acc[i]=zero4;
#pragma unroll
    for (int ks=0;ks<4;ks++){
      bf16x8 a = lds_frag(sA, rowA, 256, ks*64+kb0);
#pragma unroll
      for (int nt=0;nt<8;nt++){
        int rn = nt*16 + (lane&15);
        bf16x8 b = lds_frag(sB, rn, 256, ks*64+kb0);
        acc[nt] = MFMA(a,b,acc[nt]);
      }
    }
#pragma unroll
    for (int r=0;r<4;r++){
      bf16x8 t;
      t[0]=(bf16_t)fmaxf(acc[0][r]+bq2.x,0.f); t[1]=(bf16_t)fmaxf(acc[1][r]+bq2.y,0.f);
      t[2]=(bf16_t)fmaxf(acc[2][r]+bq2.z,0.f); t[3]=(bf16_t)fmaxf(acc[3][r]+bq2.w,0.f);
      t[4]=(bf16_t)fmaxf(acc[4][r]+bq3.x,0.f); t[5]=(bf16_t)fmaxf(acc[5][r]+bq3.y,0.f);
      t[6]=(bf16_t)fmaxf(acc[6][r]+bq3.z,0.f); t[7]=(bf16_t)fmaxf(acc[7][r]+bq3.w,0.f);
      hreg[4+r] = t;
    }
  }
  __syncthreads();   // sA (x tile) and sB free

  f32x4 o2[8];
#pragma unroll
  for (int i=0;i<8;i++) o2[i]=zero4;

#pragma unroll
  for (int half = 0; half < 2; half++){
    // write h k-half into sA (hswz layout, rows 256B of 128 hcols)
    if ((ccol >> 3) == half){
      int cb = (ccol & 7) * 32;
#pragma unroll
      for (int r=0;r<4;r++){
        int row = crow + r;
        *(bf16x8*)(sA + row*256 + hswz(row, cb))      = hreg[r];
        *(bf16x8*)(sA + row*256 + hswz(row, cb + 16)) = hreg[4+r];
      }
    }
    // write W2 k-half (reg-staged)
#pragma unroll
    for (int i=0;i<4;i++) *(f32x4*)(sB + tid*16 + i*8192) = wbuf[i];
    __syncthreads();
    // issue loads for W2 k-half1 during GEMM2a
    if (half == 0){
#pragma unroll
      for (int i=0;i<4;i++){
        int o = tid*16 + i*8192;
        wbuf[i] = *(const f32x4*)(img2 + (o >> 8)*512 + 256 + (o & 255));
      }
    }
    // GEMM2 over this k-half
#pragma unroll
    for (int ks=0;ks<4;ks++){
      const char* ap = sA + rowA*256 + hswz(rowA, ks*64+kb0);
      bf16x8 a = *(const bf16x8*)ap;
#pragma unroll
      for (int nt=0;nt<8;nt++){
        int rn = nt*16 + (lane&15);
        bf16x8 b = lds_frag(sB, rn, 256, ks*64+kb0);
        o2[nt] = MFMA(a,b,o2[nt]);
      }
    }
    __syncthreads();
  }

  // epilogue: vectorized (logical cols ccol*8..+7, W2 mode-1)
  float4 b20 = *(const float4*)(b2 + ccol*8);
  float4 b21 = *(const float4*)(b2 + ccol*8 + 4);
  float s1[8], s2[8];
#pragma unroll
  for (int j=0;j<8;j++){ s1[j]=0.f; s2[j]=0.f; }
#pragma unroll
  for (int r=0;r<4;r++){
    int grow = r0 + crow + r;
    float val[8];
    if (grow < M){
      const float4* xp = (const float4*)(xio + (size_t)grow*DIM + ccol*8);
      float4 u0 = xp[0], u1 = xp[1];
      val[0]=u0.x*sc0.x+sh0.x + o2[0][r]+b20.x; val[1]=u0.y*sc0.y+sh0.y + o2[1][r]+b20.y;
      val[2]=u0.z*sc0.z+sh0.z + o2[2][r]+b20.z; val[3]=u0.w*sc0.w+sh0.w + o2[3][r]+b20.w;
      val[4]=u1.x*sc1.x+sh1.x + o2[4][r]+b21.x; val[5]=u1.y*sc1.y+sh1.y + o2[5][r]+b21.y;
      val[6]=u1.z*sc1.z+sh1.z + o2[6][r]+b21.z; val[7]=u1.w*sc1.w+sh1.w + o2[7][r]+b21.w;
      float4 o0 = {val[0],val[1],val[2],val[3]};
      float4 o1 = {val[4],val[5],val[6],val[7]};
      float4* op = (float4*)(xio + (size_t)grow*DIM + ccol*8);
      op[0] = o0; op[1] = o1;
    } else {
#pragma unroll
      for (int j=0;j<8;j++) val[j]=0.f;
    }
#pragma unroll
    for (int j=0;j<8;j++){ s1[j] += val[j]; s2[j] += val[j]*val[j]; }
  }
#pragma unroll
  for (int j=0;j<8;j++){
    s1[j] += __shfl_xor(s1[j], 16); s1[j] += __shfl_xor(s1[j], 32);
    s2[j] += __shfl_xor(s2[j], 16); s2[j] += __shfl_xor(s2[j], 32);
  }
  if (lane < 16){
#pragma unroll
    for (int j=0;j<8;j++){
      atomicAdd(&sStats[ccol*8 + j], s1[j]);
      atomicAdd(&sStats[128 + ccol*8 + j], s2[j]);
    }
  }
  __syncthreads();
  if (tid < 256) unsafeAtomicAdd(&stats2[tid], sStats[tid]);
}

// ---------------- stats -> scale/shift ----------------
struct FinArgs { const float* st; const float* g; const float* b; float* ss; float invM; };

__global__ void k_finstats(FinArgs a0, FinArgs a1){
  FinArgs a = (blockIdx.x == 0) ? a0 : a1;
  int c = threadIdx.x;
  float mean = a.st[c] * a.invM;
  float var  = a.st[128 + c] * a.invM - mean * mean;
  float scl  = a.g[c] * rsqrtf(var + 1e-5f);
  a.ss[c] = scl;
  a.ss[128 + c] = a.b[c] - mean * scl;
}

// ---------------- in-place normalize ----------------
__global__ void k_norm(float* __restrict__ x, const float* __restrict__ ss, long long n4){
  for (long long i = (long long)blockIdx.x * blockDim.x + threadIdx.x; i < n4;
       i += (long long)gridDim.x * blockDim.x){
    float4* p = (float4*)x + i;
    float4 t = *p;
    int c0 = (int)((i * 4) & 127);
    t.x = t.x * ss[c0]     + ss[128 + c0];
    t.y = t.y * ss[c0 + 1] + ss[128 + c0 + 1];
    t.z = t.z * ss[c0 + 2] + ss[128 + c0 + 2];
    t.w = t.w * ss[c0 + 3] + ss[128 + c0 + 3];
    *p = t;
  }
}

extern "C" void kernel_launch(void* const* d_in, const int* in_sizes, int n_in,
                              void* d_out, int out_size, void* d_ws, size_t ws_size,
                              hipStream_t stream)
{
  const float* v    = (const float*)d_in[0];
  const float* e    = (const float*)d_in[1];
  const float* envl = (const float*)d_in[2];
  const int*   src  = (const int*)d_in[3];
  const int*   dst  = (const int*)d_in[4];
  const float* bOv  = (const float*)d_in[10];
  const float* bOe  = (const float*)d_in[12];
  const float* g1v  = (const float*)d_in[13];
  const float* b1vn = (const float*)d_in[14];
  const float* g1e  = (const float*)d_in[15];
  const float* b1en = (const float*)d_in[16];
  const float* g2v  = (const float*)d_in[17];
  const float* b2vn = (const float*)d_in[18];
  const float* g2e  = (const float*)d_in[19];
  const float* b2en = (const float*)d_in[20];
  const float* b1vf = (const float*)d_in[22];
  const float* b2vf = (const float*)d_in[24];
  const float* b1ef = (const float*)d_in[26];
  const float* b2ef = (const float*)d_in[28];

  float* out_v = (float*)d_out;
  float* out_e = out_v + (size_t)N_NODES * DIM;

  char* ws = (char*)d_ws;
  const size_t IMG_OFF = 0;                        // 458752 B of bf16 weight images
  const size_t QB_OFF  = 458752;                   // bf16 Q  (N*128*2 = 12.8MB)
  const size_t KB_OFF  = QB_OFF  + 12800000;       // bf16 K
  const size_t VB_OFF  = KB_OFF  + 12800000;       // bf16 V
  const size_t VA_OFF  = VB_OFF  + 12800000;       // bf16 vAttn
  const size_t SV_OFF  = VA_OFF  + 12800000;       // s per edge per head: E*8*4 = 16MB
  const size_t CSR_OFF = SV_OFF  + 16000000;       // E ints
  const size_t RP_OFF  = CSR_OFF + 2000000;        // N+1 ints
  const size_t WP_OFF  = RP_OFF  + 200016;         // N ints
  const size_t CNT_OFF = WP_OFF  + 200000;         // N ints (memset 0)
  const size_t ST_OFF  = CNT_OFF + 200000;         // 1024 f (memset 0)
  const size_t SS_OFF  = ST_OFF  + 4096;           // 1024 f

  char*   img   = ws + IMG_OFF;
  bf16_t* Qb    = (bf16_t*)(ws + QB_OFF);
  bf16_t* Kb    = (bf16_t*)(ws + KB_OFF);
  bf16_t* Vb    = (bf16_t*)(ws + VB_OFF);
  bf16_t* vAttn = (bf16_t*)(ws + VA_OFF);
  float*  svp   = (float*)(ws + SV_OFF);
  int*    csr   = (int*)(ws + CSR_OFF);
  int*    rowp  = (int*)(ws + RP_OFF);
  int*    wpp   = (int*)(ws + WP_OFF);
  int*    cnt   = (int*)(ws + CNT_OFF);
  float*  st    = (float*)(ws + ST_OFF);
  float*  ssb   = (float*)(ws + SS_OFF);
  float* st_e1 = st;        float* st_v1 = st + 256;
  float* st_v2 = st + 512;  float* st_e2 = st + 768;
  float* ss_v1 = ssb;       float* ss_e1 = ssb + 256;
  float* ss_v2 = ssb + 512; float* ss_e2 = ssb + 768;

  // zero counters + stats (contiguous)
  (void)hipMemsetAsync(ws + CNT_OFF, 0, 200000 + 4096, stream);

  WPrep wp;
  const int wid[10]   = {5,6,7,8,9,11,21,23,25,27};
  const int Ks[10]    = {128,128,128,128,128,128,128,256,128,256};
  const int Ns[10]    = {128,128,128,128,128,128,256,128,256,128};
  const int modes[10] = {1,1,1,1,1,1,3,1,3,1};   // QKV/We/WO_*/W2: p8 n-perm; W1: p16 n-perm
  int cum = 0, off = 0;
  for (int i = 0; i < 10; i++){
    wp.w[i] = (const float*)d_in[wid[i]];
    wp.Kd[i] = Ks[i]; wp.Nd[i] = Ns[i];
    wp.off[i] = off; wp.cum[i] = cum; wp.mode[i] = modes[i];
    off += Ks[i]*Ns[i]*2; cum += Ks[i]*Ns[i];
  }
  k_wprep<<<896, 256, 0, stream>>>(wp, img, cum);

  // CSR build (independent of QKV)
  k_count<<<1954, 256, 0, stream>>>(dst, cnt);
  k_scan<<<1, 1024, 0, stream>>>(cnt, rowp, wpp);
  k_fill<<<1954, 256, 0, stream>>>(dst, wpp, csr);

  k_qkv<<<391, 512, 0, stream>>>(v, img, Qb, Kb, Vb, N_NODES);

  k_edge<<<3907, 512, 0, stream>>>(e, src, dst, Qb, Kb,
                                   img + 98304 /*We*/, img + 163840 /*WO_e*/, bOe,
                                   out_e, svp, st_e1, N_EDGES);

  k_agg<<<6250, 512, 0, stream>>>(rowp, csr, src, envl, svp, Vb, vAttn, N_NODES);

  k_nodeout<<<391, 512, 0, stream>>>(vAttn, v, img + 131072 /*WO_v*/, bOv,
                                     out_v, st_v1, N_NODES);

  {
    FinArgs fv{st_v1, g1v, b1vn, ss_v1, 1.f / N_NODES};
    FinArgs fe{st_e1, g1e, b1en, ss_e1, 1.f / N_EDGES};
    k_finstats<<<2, 128, 0, stream>>>(fv, fe);
  }

  k_ffn<<<391, 512, 0, stream>>>(out_v, ss_v1, img + 196608 /*W1v*/, b1vf,
                                 img + 262144 /*W2v*/, b2vf, st_v2, N_NODES);
  k_ffn<<<3907, 512, 0, stream>>>(out_e, ss_e1, img + 327680 /*W1e*/, b1ef,
                                  img + 393216 /*W2e*/, b2ef, st_e2, N_EDGES);

  {
    FinArgs fv{st_v2, g2v, b2vn, ss_v2, 1.f / N_NODES};
    FinArgs fe{st_e2, g2e, b2en, ss_e2, 1.f / N_EDGES};
    k_finstats<<<2, 128, 0, stream>>>(fv, fe);
  }

  k_norm<<<2048, 256, 0, stream>>>(out_v, ss_v2, (long long)(N_NODES) * DIM / 4);
  k_norm<<<4096, 256, 0, stream>>>(out_e, ss_e2, (long long)(N_EDGES) * DIM / 4);
}

// Round 6
// 850.829 us; speedup vs baseline: 1.0275x; 1.0275x over previous
//
#include <hip/hip_runtime.h>
#include <hip/hip_bf16.h>

#define N_NODES 50000
#define N_EDGES 500000
#define DIM 128

typedef __bf16 bf16_t;
typedef __bf16 bf16x8 __attribute__((ext_vector_type(8)));
typedef __bf16 bf16x2 __attribute__((ext_vector_type(2)));
typedef float f32x4 __attribute__((ext_vector_type(4)));

#define MFMA(a,b,c) __builtin_amdgcn_mfma_f32_16x16x32_bf16((a),(b),(c),0,0,0)

// XOR swizzle (guide G4): kills 32-way bank conflicts for 256B/512B-stride rows
__device__ __forceinline__ int swz(int row, int kbyte){ return kbyte ^ ((row & 7) << 4); }
// full 4-bit row swizzle for the h buffer (256B rows, 16-row period)
__device__ __forceinline__ int hswz(int row, int kbyte){ return kbyte ^ ((row & 15) << 4); }

__device__ __forceinline__ bf16x8 lds_frag(const char* s, int row, int rowb, int kbyte){
  return *(const bf16x8*)(s + row * rowb + swz(row, kbyte));
}

__device__ __forceinline__ void copy16(char* dst, const char* __restrict__ src, int bytes){
  for (int o = threadIdx.x * 16; o < bytes; o += blockDim.x * 16)
    *(f32x4*)(dst + o) = *(const f32x4*)(src + o);
}

// ---------------- weight prep: f32 [K][N] -> bf16 transposed swizzled image [n][k] ----------------
// mode 1: permute output-col n -> ((n&7)<<4)|(n>>3)   (thread's 8 C elems = contiguous logical cols)
// mode 3: permute output-col n -> ((n&15)<<4)|(n>>4)  (W1, N=256: 16 contiguous logical hcols/thread)
struct WPrep {
  const float* w[10];
  int Kd[10], Nd[10], off[10], cum[10], mode[10];
};

__global__ void k_wprep(WPrep d, char* img, int total){
  for (int idx = blockIdx.x * blockDim.x + threadIdx.x; idx < total; idx += gridDim.x * blockDim.x){
    int i = 0;
#pragma unroll
    for (int j = 1; j < 10; j++) if (idx >= d.cum[j]) i = j;
    int loc = idx - d.cum[i];
    int K = d.Kd[i], N = d.Nd[i];
    int n = loc / K, k = loc - n * K;
    float val = d.w[i][(size_t)k * N + n];
    int nn = n;
    if (d.mode[i] == 1) nn = ((n & 7) << 4) | (n >> 3);
    if (d.mode[i] == 3) nn = ((n & 15) << 4) | (n >> 4);
    *(bf16_t*)(img + d.off[i] + nn * (K * 2) + swz(nn, k * 2)) = (bf16_t)val;
  }
}

// ---------------- CSR build ----------------
__global__ void k_count(const int* __restrict__ dst, int* __restrict__ cnt){
  int i = blockIdx.x * blockDim.x + threadIdx.x;
  if (i < N_EDGES) atomicAdd(&cnt[dst[i]], 1);
}

__global__ __launch_bounds__(1024) void k_scan(const int* __restrict__ cnt,
                                               int* __restrict__ rowptr, int* __restrict__ wp){
  __shared__ int wsum[16];
  __shared__ int wpre[16];
  __shared__ int scarry;
  const int tid = threadIdx.x, lane = tid & 63, wv = tid >> 6;
  if (tid == 0) scarry = 0;
  for (int base = 0; base < N_NODES; base += 8192){
    int i0 = base + tid * 8;
    int v[8], p[8];
    int tsum = 0;
#pragma unroll
    for (int j = 0; j < 8; j++){
      int idx = i0 + j;
      v[j] = (idx < N_NODES) ? cnt[idx] : 0;
      p[j] = tsum; tsum += v[j];
    }
    int x = tsum;
#pragma unroll
    for (int off = 1; off < 64; off <<= 1){
      int t = __shfl_up(x, off);
      if (lane >= off) x += t;
    }
    if (lane == 63) wsum[wv] = x;
    __syncthreads();
    if (tid == 0){
      int run = scarry;
#pragma unroll
      for (int j = 0; j < 16; j++){ int t = wsum[j]; wpre[j] = run; run += t; }
      scarry = run;
    }
    __syncthreads();
    int texcl = wpre[wv] + x - tsum;
#pragma unroll
    for (int j = 0; j < 8; j++){
      int idx = i0 + j;
      if (idx < N_NODES){ rowptr[idx] = texcl + p[j]; wp[idx] = texcl + p[j]; }
    }
  }
  __syncthreads();
  if (tid == 0) rowptr[N_NODES] = scarry;
}

__global__ void k_fill(const int* __restrict__ dst, int* __restrict__ wp, int* __restrict__ csr){
  int i = blockIdx.x * blockDim.x + threadIdx.x;
  if (i < N_EDGES){
    int p = atomicAdd(&wp[dst[i]], 1);
    csr[p] = i;
  }
}

// ---------------- QKV: [M,128] @ 3x [128,128] -> bf16 outputs (mode-1 weights -> vector stores) ----------------
__global__ __launch_bounds__(512) void k_qkv(
    const float* __restrict__ v, const char* __restrict__ img,
    bf16_t* __restrict__ Q, bf16_t* __restrict__ K, bf16_t* __restrict__ V, int M)
{
  __shared__ __align__(16) char sm[65536];
  char* sX = sm;
  char* sW = sm + 32768;
  const int tid = threadIdx.x, lane = tid & 63, wave = tid >> 6;
  const int r0 = blockIdx.x * 128;
  for (int c = tid; c < 2048; c += 512){
    int row = c >> 4, kc = c & 15, grow = r0 + row;
    float f[8];
    if (grow < M){
      const float4* p = (const float4*)(v + (size_t)grow * DIM + kc * 8);
      float4 u0 = p[0], u1 = p[1];
      f[0]=u0.x; f[1]=u0.y; f[2]=u0.z; f[3]=u0.w;
      f[4]=u1.x; f[5]=u1.y; f[6]=u1.z; f[7]=u1.w;
    } else {
#pragma unroll
      for (int j=0;j<8;j++) f[j] = 0.f;
    }
    bf16x8 o;
#pragma unroll
    for (int j=0;j<8;j++) o[j] = (bf16_t)f[j];
    *(bf16x8*)(sX + row * 256 + swz(row, kc * 16)) = o;
  }
  const int rowA = wave * 16 + (lane & 15);
  const int kb0 = (lane >> 4) * 16;
  const int crow = wave*16 + (lane >> 4)*4;
  const int ccol = lane & 15;
  const f32x4 zero4 = {0.f, 0.f, 0.f, 0.f};
#pragma unroll
  for (int w3 = 0; w3 < 3; w3++){
    __syncthreads();            // staging done / prev GEMM done with sW
    copy16(sW, img + w3 * 32768, 32768);
    __syncthreads();
    f32x4 acc[8];
#pragma unroll
    for (int b=0;b<8;b++) acc[b] = zero4;
#pragma unroll
    for (int ks=0; ks<4; ks++){
      bf16x8 a = lds_frag(sX, rowA, 256, ks*64 + kb0);
#pragma unroll
      for (int nt=0; nt<8; nt++){
        int rn = nt*16 + (lane & 15);
        bf16x8 b = lds_frag(sW, rn, 256, ks*64 + kb0);
        acc[nt] = MFMA(a, b, acc[nt]);
      }
    }
    bf16_t* o = (w3 == 0) ? Q : ((w3 == 1) ? K : V);
    // mode-1 perm: acc[nt] = logical col ccol*8+nt -> one bf16x8 store per row
#pragma unroll
    for (int r=0; r<4; r++){
      int grow = r0 + crow + r;
      if (grow < M){
        bf16x8 t;
#pragma unroll
        for (int nt=0; nt<8; nt++) t[nt] = (bf16_t)acc[nt][r];
        *(bf16x8*)(o + (size_t)grow * DIM + ccol*8) = t;
      }
    }
  }
}

// ---------------- fused edge attention ----------------
// Footprint staging (rows crow..+3, cols ccol*8..+7); bf16 residual kept in regs -> no e re-read.
__global__ __launch_bounds__(512, 4) void k_edge(
    const float* __restrict__ e,
    const int* __restrict__ src, const int* __restrict__ dst,
    const bf16_t* __restrict__ Qb, const bf16_t* __restrict__ Kb,
    const char* __restrict__ imgWe, const char* __restrict__ imgWo,
    const float* __restrict__ bOe,
    float* __restrict__ e1_pre, float* __restrict__ sv,
    float* __restrict__ stats, int M)
{
  __shared__ __align__(16) char sm[66560];
  char* sW = sm;                          // 32KB: We then WO_e
  char* sX = sm + 32768;                  // 32KB: e tile, then score
  float* sStats = (float*)(sm + 65536);   // 256 f
  const int tid = threadIdx.x, lane = tid & 63, wave = tid >> 6;
  const int r0 = blockIdx.x * 128;
  const int crow = wave*16 + (lane >> 4)*4;
  const int ccol = lane & 15;
  // prefetch K[src]/Q[dst] fragments (in flight through staging + GEMM1)
  bf16x8 Kg[4], Qg[4];
#pragma unroll
  for (int r=0;r<4;r++){
    int ed = r0 + crow + r; if (ed >= M) ed = M - 1;
    int sn = src[ed], dn = dst[ed];
    Kg[r] = *(const bf16x8*)(Kb + (size_t)sn * DIM + ccol * 8);
    Qg[r] = *(const bf16x8*)(Qb + (size_t)dn * DIM + ccol * 8);
  }
  copy16(sW, imgWe, 32768);
  if (tid < 256) sStats[tid] = 0.f;
  // footprint staging: keep bf16 residual in regs
  bf16x8 eres[4];
#pragma unroll
  for (int r = 0; r < 4; r++){
    int row = crow + r, grow = r0 + row;
    bf16x8 o;
    if (grow < M){
      const float4* p = (const float4*)(e + (size_t)grow * DIM + ccol * 8);
      float4 u0 = p[0], u1 = p[1];
      o[0]=(bf16_t)u0.x; o[1]=(bf16_t)u0.y; o[2]=(bf16_t)u0.z; o[3]=(bf16_t)u0.w;
      o[4]=(bf16_t)u1.x; o[5]=(bf16_t)u1.y; o[6]=(bf16_t)u1.z; o[7]=(bf16_t)u1.w;
    } else {
#pragma unroll
      for (int j=0;j<8;j++) o[j] = (bf16_t)0.f;
    }
    eres[r] = o;
    *(bf16x8*)(sX + row * 256 + swz(row, ccol * 16)) = o;
  }
  __syncthreads();
  const int rowA = wave * 16 + (lane & 15);
  const int kb0 = (lane >> 4) * 16;
  const f32x4 zero4 = {0.f,0.f,0.f,0.f};
  f32x4 pe[8];
#pragma unroll
  for (int i=0;i<8;i++) pe[i] = zero4;
#pragma unroll
  for (int ks=0; ks<4; ks++){
    bf16x8 a = lds_frag(sX, rowA, 256, ks*64 + kb0);
#pragma unroll
    for (int nt=0; nt<8; nt++){
      int rn = nt*16 + (lane & 15);
      bf16x8 b = lds_frag(sW, rn, 256, ks*64 + kb0);
      pe[nt] = MFMA(a, b, pe[nt]);
    }
  }
  __syncthreads();   // done reading sX (e tile) and sW (We)
  copy16(sW, imgWo, 32768);               // WO_e into the same buffer (overlaps score phase)
  // score: logical col ccol*8+nt -> one bf16x8 per row (logical LDS layout)
#pragma unroll
  for (int r=0;r<4;r++){
    int row = crow + r;
    bf16x8 t;
    float hsum = 0.f;
#pragma unroll
    for (int nt=0; nt<8; nt++){
      float sc = pe[nt][r] * 0.25f * (float)Kg[r][nt] * (float)Qg[r][nt];
      t[nt] = (bf16_t)sc;
      hsum += sc;
    }
    *(bf16x8*)(sX + row*256 + swz(row, ccol*16)) = t;
    float ts = hsum + __shfl_xor(hsum, 1);   // pair covers the full 16-col head
    int ed = r0 + row;
    if (!(ccol & 1) && ed < M)
      sv[(size_t)ed*8 + (ccol >> 1)] = __expf(fminf(5.f, fmaxf(-5.f, ts)));
  }
  __syncthreads();
  // GEMM2: e_attn @ WO_e (score logical layout, WO_e mode-1)
  f32x4 a2[8];
#pragma unroll
  for (int i=0;i<8;i++) a2[i] = zero4;
#pragma unroll
  for (int ks=0; ks<4; ks++){
    bf16x8 a = lds_frag(sX, rowA, 256, ks*64 + kb0);
#pragma unroll
    for (int nt=0; nt<8; nt++){
      int rn = nt*16 + (lane & 15);
      bf16x8 b = lds_frag(sW, rn, 256, ks*64 + kb0);
      a2[nt] = MFMA(a, b, a2[nt]);
    }
  }
  // epilogue: residual from regs, vectorized stores
  float4 bo0 = *(const float4*)(bOe + ccol*8);
  float4 bo1 = *(const float4*)(bOe + ccol*8 + 4);
  float s1[8], s2[8];
#pragma unroll
  for (int j=0;j<8;j++){ s1[j]=0.f; s2[j]=0.f; }
#pragma unroll
  for (int r=0; r<4; r++){
    int ed = r0 + crow + r;
    float val[8];
    val[0]=a2[0][r]+(float)eres[r][0]+bo0.x; val[1]=a2[1][r]+(float)eres[r][1]+bo0.y;
    val[2]=a2[2][r]+(float)eres[r][2]+bo0.z; val[3]=a2[3][r]+(float)eres[r][3]+bo0.w;
    val[4]=a2[4][r]+(float)eres[r][4]+bo1.x; val[5]=a2[5][r]+(float)eres[r][5]+bo1.y;
    val[6]=a2[6][r]+(float)eres[r][6]+bo1.z; val[7]=a2[7][r]+(float)eres[r][7]+bo1.w;
    if (ed < M){
      float4 o0 = {val[0],val[1],val[2],val[3]};
      float4 o1 = {val[4],val[5],val[6],val[7]};
      float4* op = (float4*)(e1_pre + (size_t)ed*DIM + ccol*8);
      op[0] = o0; op[1] = o1;
    } else {
#pragma unroll
      for (int j=0;j<8;j++) val[j]=0.f;
    }
#pragma unroll
    for (int j=0;j<8;j++){ s1[j] += val[j]; s2[j] += val[j]*val[j]; }
  }
#pragma unroll
  for (int j=0;j<8;j++){
    s1[j] += __shfl_xor(s1[j], 16); s1[j] += __shfl_xor(s1[j], 32);
    s2[j] += __shfl_xor(s2[j], 16); s2[j] += __shfl_xor(s2[j], 32);
  }
  if (lane < 16){
#pragma unroll
    for (int j=0;j<8;j++){
      atomicAdd(&sStats[ccol*8 + j], s1[j]);
      atomicAdd(&sStats[128 + ccol*8 + j], s2[j]);
    }
  }
  __syncthreads();
  if (tid < 256) unsafeAtomicAdd(&stats[tid], sStats[tid]);
}

// ---------------- aggregation: one wave per node, CSR walk, no atomics ----------------
__global__ __launch_bounds__(512) void k_agg(
    const int* __restrict__ rowptr, const int* __restrict__ csr,
    const int* __restrict__ src, const float* __restrict__ envl,
    const float* __restrict__ sv, const bf16_t* __restrict__ V,
    bf16_t* __restrict__ vAttn, int M)
{
  const int wave = threadIdx.x >> 6, lane = threadIdx.x & 63;
  const int n = blockIdx.x * 8 + wave;
  if (n >= M) return;
  const int beg = rowptr[n], end = rowptr[n + 1];
  const int h = lane >> 3;           // head of cols (2*lane, 2*lane+1)
  float ax = 0.f, ay = 0.f, zacc = 0.f;
  for (int i = beg; i < end; i++){
    int eid = csr[i];
    int sn = src[eid];
    float s = sv[(size_t)eid * 8 + h];
    float env = envl[eid];
    const bf16x2 vv = *(const bf16x2*)(V + (size_t)sn * DIM + lane * 2);
    float w = env * s;
    ax += (float)vv[0] * w; ay += (float)vv[1] * w;
    zacc += s;
  }
  float inv = 1.f / (zacc + 1e-6f);
  bf16x2 o; o[0] = (bf16_t)(ax * inv); o[1] = (bf16_t)(ay * inv);
  *(bf16x2*)(vAttn + (size_t)n * DIM + lane * 2) = o;
}

// ---------------- node: v1_pre = v + v_attn@WO_v + bOv; stats (WO_v mode-1) ----------------
__global__ __launch_bounds__(512) void k_nodeout(
    const bf16_t* __restrict__ vAttn, const float* __restrict__ v,
    const char* __restrict__ imgWo, const float* __restrict__ bOv,
    float* __restrict__ v1_pre, float* __restrict__ stats, int M)
{
  __shared__ __align__(16) char sm[66560];
  char* sW = sm;
  char* sX = sm + 32768;
  float* sStats = (float*)(sm + 65536);
  const int tid = threadIdx.x, lane = tid & 63, wave = tid >> 6;
  const int r0 = blockIdx.x * 128;
  copy16(sW, imgWo, 32768);
  if (tid < 256) sStats[tid] = 0.f;
  for (int c = tid; c < 2048; c += 512){
    int row = c >> 4, kc = c & 15, grow = r0 + row;
    bf16x8 o;
    if (grow < M){
      o = *(const bf16x8*)(vAttn + (size_t)grow * DIM + kc * 8);
    } else {
#pragma unroll
      for (int j=0;j<8;j++) o[j] = (bf16_t)0.f;
    }
    *(bf16x8*)(sX + row*256 + swz(row, kc*16)) = o;
  }
  __syncthreads();
  const int rowA = wave*16 + (lane & 15);
  const int kb0 = (lane >> 4)*16;
  const f32x4 zero4 = {0.f,0.f,0.f,0.f};
  f32x4 acc[8];
#pragma unroll
  for (int i=0;i<8;i++) acc[i]=zero4;
#pragma unroll
  for (int ks=0;ks<4;ks++){
    bf16x8 a = lds_frag(sX, rowA, 256, ks*64+kb0);
#pragma unroll
    for (int nt=0;nt<8;nt++){
      int rn = nt*16 + (lane&15);
      bf16x8 b = lds_frag(sW, rn, 256, ks*64+kb0);
      acc[nt] = MFMA(a,b,acc[nt]);
    }
  }
  const int crow = wave*16 + (lane>>4)*4;
  const int ccol = lane & 15;
  float4 bo0 = *(const float4*)(bOv + ccol*8);
  float4 bo1 = *(const float4*)(bOv + ccol*8 + 4);
  float s1[8], s2[8];
#pragma unroll
  for (int j=0;j<8;j++){ s1[j]=0.f; s2[j]=0.f; }
#pragma unroll
  for (int r=0;r<4;r++){
    int grow = r0 + crow + r;
    float val[8];
    if (grow < M){
      const float4* vp = (const float4*)(v + (size_t)grow*DIM + ccol*8);
      float4 v0 = vp[0], v1 = vp[1];
      val[0]=acc[0][r]+v0.x+bo0.x; val[1]=acc[1][r]+v0.y+bo0.y;
      val[2]=acc[2][r]+v0.z+bo0.z; val[3]=acc[3][r]+v0.w+bo0.w;
      val[4]=acc[4][r]+v1.x+bo1.x; val[5]=acc[5][r]+v1.y+bo1.y;
      val[6]=acc[6][r]+v1.z+bo1.z; val[7]=acc[7][r]+v1.w+bo1.w;
      float4 o0 = {val[0],val[1],val[2],val[3]};
      float4 o1 = {val[4],val[5],val[6],val[7]};
      float4* op = (float4*)(v1_pre + (size_t)grow*DIM + ccol*8);
      op[0] = o0; op[1] = o1;
    } else {
#pragma unroll
      for (int j=0;j<8;j++) val[j]=0.f;
    }
#pragma unroll
    for (int j=0;j<8;j++){ s1[j] += val[j]; s2[j] += val[j]*val[j]; }
  }
#pragma unroll
  for (int j=0;j<8;j++){
    s1[j] += __shfl_xor(s1[j], 16); s1[j] += __shfl_xor(s1[j], 32);
    s2[j] += __shfl_xor(s2[j], 16); s2[j] += __shfl_xor(s2[j], 32);
  }
  if (lane < 16){
#pragma unroll
    for (int j=0;j<8;j++){
      atomicAdd(&sStats[ccol*8 + j], s1[j]);
      atomicAdd(&sStats[128 + ccol*8 + j], s2[j]);
    }
  }
  __syncthreads();
  if (tid < 256) unsafeAtomicAdd(&stats[tid], sStats[tid]);
}

// ---------------- fused FFN ----------------
// W1 mode-3 (16 contiguous logical hcols/thread, h in bf16 VGPRs); W2 mode-1 (vector epilogue).
// Footprint staging keeps bf16 x1 in regs -> no epilogue re-read of xio.
__global__ __launch_bounds__(512, 4) void k_ffn(
    float* __restrict__ xio, const float* __restrict__ ss1,
    const char* __restrict__ img1, const float* __restrict__ b1,
    const char* __restrict__ img2, const float* __restrict__ b2,
    float* __restrict__ stats2, int M)
{
  __shared__ __align__(16) char sm[66560];
  char* sA = sm;           // x1 tile (bf16); later h halves (hswz layout)
  char* sB = sm + 32768;   // W1h0, W1h1, W2k0, W2k1
  float* sStats = (float*)(sm + 65536);
  const int tid = threadIdx.x, lane = tid & 63, wave = tid >> 6;
  const int r0 = blockIdx.x * 128;
  const int rowA = wave*16 + (lane & 15);
  const int kb0 = (lane >> 4) * 16;
  const int crow = wave*16 + (lane >> 4)*4;
  const int ccol = lane & 15;
  const f32x4 zero4 = {0.f,0.f,0.f,0.f};

  // BN scale/shift for this thread's 8 contiguous cols
  float4 sc0 = *(const float4*)(ss1 + ccol*8);
  float4 sc1 = *(const float4*)(ss1 + ccol*8 + 4);
  float4 sh0 = *(const float4*)(ss1 + 128 + ccol*8);
  float4 sh1 = *(const float4*)(ss1 + 128 + ccol*8 + 4);
  // biases for this thread's 16 contiguous logical hcols
  const float4* bq = (const float4*)(b1 + ccol * 16);
  float4 bq0 = bq[0], bq1 = bq[1], bq2 = bq[2], bq3 = bq[3];

  // phase 1: stage x1 tile (footprint), keep bf16 x1 in regs; + W1 half0
  copy16(sB, img1, 32768);
  if (tid < 256) sStats[tid] = 0.f;
  bf16x8 xres[4];
#pragma unroll
  for (int r = 0; r < 4; r++){
    int row = crow + r, grow = r0 + row;
    bf16x8 o;
    if (grow < M){
      const float4* p = (const float4*)(xio + (size_t)grow*DIM + ccol*8);
      float4 u0 = p[0], u1 = p[1];
      o[0]=(bf16_t)(u0.x*sc0.x+sh0.x); o[1]=(bf16_t)(u0.y*sc0.y+sh0.y);
      o[2]=(bf16_t)(u0.z*sc0.z+sh0.z); o[3]=(bf16_t)(u0.w*sc0.w+sh0.w);
      o[4]=(bf16_t)(u1.x*sc1.x+sh1.x); o[5]=(bf16_t)(u1.y*sc1.y+sh1.y);
      o[6]=(bf16_t)(u1.z*sc1.z+sh1.z); o[7]=(bf16_t)(u1.w*sc1.w+sh1.w);
    } else {
#pragma unroll
      for (int j=0;j<8;j++) o[j]=(bf16_t)0.f;
    }
    xres[r] = o;
    *(bf16x8*)(sA + row*256 + swz(row, ccol*16)) = o;
  }
  __syncthreads();

  bf16x8 hreg[8];   // [r] = half0 hcols (nt 0..7), [4+r] = half1 (nt 8..15)
  f32x4 wbuf[4];    // reg-staged next weight chunk

  // phase 2: GEMM1a (+ issue W1 half1 loads)
#pragma unroll
  for (int i=0;i<4;i++) wbuf[i] = *(const f32x4*)(img1 + 32768 + tid*16 + i*8192);
  {
    f32x4 acc[8];
#pragma unroll
    for (int i=0;i<8;i++) acc[i]=zero4;
#pragma unroll
    for (int ks=0;ks<4;ks++){
      bf16x8 a = lds_frag(sA, rowA, 256, ks*64+kb0);
#pragma unroll
      for (int nt=0;nt<8;nt++){
        int rn = nt*16 + (lane&15);
        bf16x8 b = lds_frag(sB, rn, 256, ks*64+kb0);
        acc[nt] = MFMA(a,b,acc[nt]);
      }
    }
#pragma unroll
    for (int r=0;r<4;r++){
      bf16x8 t;
      t[0]=(bf16_t)fmaxf(acc[0][r]+bq0.x,0.f); t[1]=(bf16_t)fmaxf(acc[1][r]+bq0.y,0.f);
      t[2]=(bf16_t)fmaxf(acc[2][r]+bq0.z,0.f); t[3]=(bf16_t)fmaxf(acc[3][r]+bq0.w,0.f);
      t[4]=(bf16_t)fmaxf(acc[4][r]+bq1.x,0.f); t[5]=(bf16_t)fmaxf(acc[5][r]+bq1.y,0.f);
      t[6]=(bf16_t)fmaxf(acc[6][r]+bq1.z,0.f); t[7]=(bf16_t)fmaxf(acc[7][r]+bq1.w,0.f);
      hreg[r] = t;
    }
  }
  __syncthreads();
  // phase 3: write W1 half1
#pragma unroll
  for (int i=0;i<4;i++) *(f32x4*)(sB + tid*16 + i*8192) = wbuf[i];
  __syncthreads();
  // phase 4: GEMM1b (+ issue W2 k-half0 loads)
#pragma unroll
  for (int i=0;i<4;i++){
    int o = tid*16 + i*8192;
    wbuf[i] = *(const f32x4*)(img2 + (o >> 8)*512 + (o & 255));
  }
  {
    f32x4 acc[8];
#pragma unroll
    for (int i=0;i<8;i++) acc[i]=zero4;
#pragma unroll
    for (int ks=0;ks<4;ks++){
      bf16x8 a = lds_frag(sA, rowA, 256, ks*64+kb0);
#pragma unroll
      for (int nt=0;nt<8;nt++){
        int rn = nt*16 + (lane&15);
        bf16x8 b = lds_frag(sB, rn, 256, ks*64+kb0);
        acc[nt] = MFMA(a,b,acc[nt]);
      }
    }
#pragma unroll
    for (int r=0;r<4;r++){
      bf16x8 t;
      t[0]=(bf16_t)fmaxf(acc[0][r]+bq2.x,0.f); t[1]=(bf16_t)fmaxf(acc[1][r]+bq2.y,0.f);
      t[2]=(bf16_t)fmaxf(acc[2][r]+bq2.z,0.f); t[3]=(bf16_t)fmaxf(acc[3][r]+bq2.w,0.f);
      t[4]=(bf16_t)fmaxf(acc[4][r]+bq3.x,0.f); t[5]=(bf16_t)fmaxf(acc[5][r]+bq3.y,0.f);
      t[6]=(bf16_t)fmaxf(acc[6][r]+bq3.z,0.f); t[7]=(bf16_t)fmaxf(acc[7][r]+bq3.w,0.f);
      hreg[4+r] = t;
    }
  }
  __syncthreads();   // sA (x tile) and sB free

  f32x4 o2[8];
#pragma unroll
  for (int i=0;i<8;i++) o2[i]=zero4;

#pragma unroll
  for (int half = 0; half < 2; half++){
    // write h k-half into sA (hswz layout, rows 256B of 128 hcols)
    if ((ccol >> 3) == half){
      int cb = (ccol & 7) * 32;
#pragma unroll
      for (int r=0;r<4;r++){
        int row = crow + r;
        *(bf16x8*)(sA + row*256 + hswz(row, cb))      = hreg[r];
        *(bf16x8*)(sA + row*256 + hswz(row, cb + 16)) = hreg[4+r];
      }
    }
    // write W2 k-half (reg-staged)
#pragma unroll
    for (int i=0;i<4;i++) *(f32x4*)(sB + tid*16 + i*8192) = wbuf[i];
    __syncthreads();
    // issue loads for W2 k-half1 during GEMM2a
    if (half == 0){
#pragma unroll
      for (int i=0;i<4;i++){
        int o = tid*16 + i*8192;
        wbuf[i] = *(const f32x4*)(img2 + (o >> 8)*512 + 256 + (o & 255));
      }
    }
    // GEMM2 over this k-half
#pragma unroll
    for (int ks=0;ks<4;ks++){
      const char* ap = sA + rowA*256 + hswz(rowA, ks*64+kb0);
      bf16x8 a = *(const bf16x8*)ap;
#pragma unroll
      for (int nt=0;nt<8;nt++){
        int rn = nt*16 + (lane&15);
        bf16x8 b = lds_frag(sB, rn, 256, ks*64+kb0);
        o2[nt] = MFMA(a,b,o2[nt]);
      }
    }
    __syncthreads();
  }

  // epilogue: residual from regs (x1 bf16), vectorized stores
  float4 b20 = *(const float4*)(b2 + ccol*8);
  float4 b21 = *(const float4*)(b2 + ccol*8 + 4);
  float s1[8], s2[8];
#pragma unroll
  for (int j=0;j<8;j++){ s1[j]=0.f; s2[j]=0.f; }
#pragma unroll
  for (int r=0;r<4;r++){
    int grow = r0 + crow + r;
    float val[8];
    val[0]=(float)xres[r][0]+o2[0][r]+b20.x; val[1]=(float)xres[r][1]+o2[1][r]+b20.y;
    val[2]=(float)xres[r][2]+o2[2][r]+b20.z; val[3]=(float)xres[r][3]+o2[3][r]+b20.w;
    val[4]=(float)xres[r][4]+o2[4][r]+b21.x; val[5]=(float)xres[r][5]+o2[5][r]+b21.y;
    val[6]=(float)xres[r][6]+o2[6][r]+b21.z; val[7]=(float)xres[r][7]+o2[7][r]+b21.w;
    if (grow < M){
      float4 o0 = {val[0],val[1],val[2],val[3]};
      float4 o1 = {val[4],val[5],val[6],val[7]};
      float4* op = (float4*)(xio + (size_t)grow*DIM + ccol*8);
      op[0] = o0; op[1] = o1;
    } else {
#pragma unroll
      for (int j=0;j<8;j++) val[j]=0.f;
    }
#pragma unroll
    for (int j=0;j<8;j++){ s1[j] += val[j]; s2[j] += val[j]*val[j]; }
  }
#pragma unroll
  for (int j=0;j<8;j++){
    s1[j] += __shfl_xor(s1[j], 16); s1[j] += __shfl_xor(s1[j], 32);
    s2[j] += __shfl_xor(s2[j], 16); s2[j] += __shfl_xor(s2[j], 32);
  }
  if (lane < 16){
#pragma unroll
    for (int j=0;j<8;j++){
      atomicAdd(&sStats[ccol*8 + j], s1[j]);
      atomicAdd(&sStats[128 + ccol*8 + j], s2[j]);
    }
  }
  __syncthreads();
  if (tid < 256) unsafeAtomicAdd(&stats2[tid], sStats[tid]);
}

// ---------------- stats -> scale/shift ----------------
struct FinArgs { const float* st; const float* g; const float* b; float* ss; float invM; };

__global__ void k_finstats(FinArgs a0, FinArgs a1){
  FinArgs a = (blockIdx.x == 0) ? a0 : a1;
  int c = threadIdx.x;
  float mean = a.st[c] * a.invM;
  float var  = a.st[128 + c] * a.invM - mean * mean;
  float scl  = a.g[c] * rsqrtf(var + 1e-5f);
  a.ss[c] = scl;
  a.ss[128 + c] = a.b[c] - mean * scl;
}

// ---------------- in-place normalize ----------------
__global__ void k_norm(float* __restrict__ x, const float* __restrict__ ss, long long n4){
  for (long long i = (long long)blockIdx.x * blockDim.x + threadIdx.x; i < n4;
       i += (long long)gridDim.x * blockDim.x){
    float4* p = (float4*)x + i;
    float4 t = *p;
    int c0 = (int)((i * 4) & 127);
    t.x = t.x * ss[c0]     + ss[128 + c0];
    t.y = t.y * ss[c0 + 1] + ss[128 + c0 + 1];
    t.z = t.z * ss[c0 + 2] + ss[128 + c0 + 2];
    t.w = t.w * ss[c0 + 3] + ss[128 + c0 + 3];
    *p = t;
  }
}

extern "C" void kernel_launch(void* const* d_in, const int* in_sizes, int n_in,
                              void* d_out, int out_size, void* d_ws, size_t ws_size,
                              hipStream_t stream)
{
  const float* v    = (const float*)d_in[0];
  const float* e    = (const float*)d_in[1];
  const float* envl = (const float*)d_in[2];
  const int*   src  = (const int*)d_in[3];
  const int*   dst  = (const int*)d_in[4];
  const float* bOv  = (const float*)d_in[10];
  const float* bOe  = (const float*)d_in[12];
  const float* g1v  = (const float*)d_in[13];
  const float* b1vn = (const float*)d_in[14];
  const float* g1e  = (const float*)d_in[15];
  const float* b1en = (const float*)d_in[16];
  const float* g2v  = (const float*)d_in[17];
  const float* b2vn = (const float*)d_in[18];
  const float* g2e  = (const float*)d_in[19];
  const float* b2en = (const float*)d_in[20];
  const float* b1vf = (const float*)d_in[22];
  const float* b2vf = (const float*)d_in[24];
  const float* b1ef = (const float*)d_in[26];
  const float* b2ef = (const float*)d_in[28];

  float* out_v = (float*)d_out;
  float* out_e = out_v + (size_t)N_NODES * DIM;

  char* ws = (char*)d_ws;
  const size_t IMG_OFF = 0;                        // 458752 B of bf16 weight images
  const size_t QB_OFF  = 458752;                   // bf16 Q  (N*128*2 = 12.8MB)
  const size_t KB_OFF  = QB_OFF  + 12800000;       // bf16 K
  const size_t VB_OFF  = KB_OFF  + 12800000;       // bf16 V
  const size_t VA_OFF  = VB_OFF  + 12800000;       // bf16 vAttn
  const size_t SV_OFF  = VA_OFF  + 12800000;       // s per edge per head: E*8*4 = 16MB
  const size_t CSR_OFF = SV_OFF  + 16000000;       // E ints
  const size_t RP_OFF  = CSR_OFF + 2000000;        // N+1 ints
  const size_t WP_OFF  = RP_OFF  + 200016;         // N ints
  const size_t CNT_OFF = WP_OFF  + 200000;         // N ints (memset 0)
  const size_t ST_OFF  = CNT_OFF + 200000;         // 1024 f (memset 0)
  const size_t SS_OFF  = ST_OFF  + 4096;           // 1024 f

  char*   img   = ws + IMG_OFF;
  bf16_t* Qb    = (bf16_t*)(ws + QB_OFF);
  bf16_t* Kb    = (bf16_t*)(ws + KB_OFF);
  bf16_t* Vb    = (bf16_t*)(ws + VB_OFF);
  bf16_t* vAttn = (bf16_t*)(ws + VA_OFF);
  float*  svp   = (float*)(ws + SV_OFF);
  int*    csr   = (int*)(ws + CSR_OFF);
  int*    rowp  = (int*)(ws + RP_OFF);
  int*    wpp   = (int*)(ws + WP_OFF);
  int*    cnt   = (int*)(ws + CNT_OFF);
  float*  st    = (float*)(ws + ST_OFF);
  float*  ssb   = (float*)(ws + SS_OFF);
  float* st_e1 = st;        float* st_v1 = st + 256;
  float* st_v2 = st + 512;  float* st_e2 = st + 768;
  float* ss_v1 = ssb;       float* ss_e1 = ssb + 256;
  float* ss_v2 = ssb + 512; float* ss_e2 = ssb + 768;

  // zero counters + stats (contiguous)
  (void)hipMemsetAsync(ws + CNT_OFF, 0, 200000 + 4096, stream);

  WPrep wp;
  const int wid[10]   = {5,6,7,8,9,11,21,23,25,27};
  const int Ks[10]    = {128,128,128,128,128,128,128,256,128,256};
  const int Ns[10]    = {128,128,128,128,128,128,256,128,256,128};
  const int modes[10] = {1,1,1,1,1,1,3,1,3,1};   // QKV/We/WO_*/W2: p8 n-perm; W1: p16 n-perm
  int cum = 0, off = 0;
  for (int i = 0; i < 10; i++){
    wp.w[i] = (const float*)d_in[wid[i]];
    wp.Kd[i] = Ks[i]; wp.Nd[i] = Ns[i];
    wp.off[i] = off; wp.cum[i] = cum; wp.mode[i] = modes[i];
    off += Ks[i]*Ns[i]*2; cum += Ks[i]*Ns[i];
  }
  k_wprep<<<896, 256, 0, stream>>>(wp, img, cum);

  // CSR build (independent of QKV)
  k_count<<<1954, 256, 0, stream>>>(dst, cnt);
  k_scan<<<1, 1024, 0, stream>>>(cnt, rowp, wpp);
  k_fill<<<1954, 256, 0, stream>>>(dst, wpp, csr);

  k_qkv<<<391, 512, 0, stream>>>(v, img, Qb, Kb, Vb, N_NODES);

  k_edge<<<3907, 512, 0, stream>>>(e, src, dst, Qb, Kb,
                                   img + 98304 /*We*/, img + 163840 /*WO_e*/, bOe,
                                   out_e, svp, st_e1, N_EDGES);

  k_agg<<<6250, 512, 0, stream>>>(rowp, csr, src, envl, svp, Vb, vAttn, N_NODES);

  k_nodeout<<<391, 512, 0, stream>>>(vAttn, v, img + 131072 /*WO_v*/, bOv,
                                     out_v, st_v1, N_NODES);

  {
    FinArgs fv{st_v1, g1v, b1vn, ss_v1, 1.f / N_NODES};
    FinArgs fe{st_e1, g1e, b1en, ss_e1, 1.f / N_EDGES};
    k_finstats<<<2, 128, 0, stream>>>(fv, fe);
  }

  k_ffn<<<391, 512, 0, stream>>>(out_v, ss_v1, img + 196608 /*W1v*/, b1vf,
                                 img + 262144 /*W2v*/, b2vf, st_v2, N_NODES);
  k_ffn<<<3907, 512, 0, stream>>>(out_e, ss_e1, img + 327680 /*W1e*/, b1ef,
                                  img + 393216 /*W2e*/, b2ef, st_e2, N_EDGES);

  {
    FinArgs fv{st_v2, g2v, b2vn, ss_v2, 1.f / N_NODES};
    FinArgs fe{st_e2, g2e, b2en, ss_e2, 1.f / N_EDGES};
    k_finstats<<<2, 128, 0, stream>>>(fv, fe);
  }

  k_norm<<<2048, 256, 0, stream>>>(out_v, ss_v2, (long long)(N_NODES) * DIM / 4);
  k_norm<<<4096, 256, 0, stream>>>(out_e, ss_e2, (long long)(N_EDGES) * DIM / 4);
}

// Round 7
// 803.866 us; speedup vs baseline: 1.0876x; 1.0584x over previous
//
#include <hip/hip_runtime.h>
#include <hip/hip_bf16.h>

#define N_NODES 50000
#define N_EDGES 500000
#define DIM 128

typedef __bf16 bf16_t;
typedef __bf16 bf16x8 __attribute__((ext_vector_type(8)));
typedef __bf16 bf16x2 __attribute__((ext_vector_type(2)));
typedef float f32x4 __attribute__((ext_vector_type(4)));

#define MFMA(a,b,c) __builtin_amdgcn_mfma_f32_16x16x32_bf16((a),(b),(c),0,0,0)

// XOR swizzle (guide G4): kills 32-way bank conflicts for 256B/512B-stride rows
__device__ __forceinline__ int swz(int row, int kbyte){ return kbyte ^ ((row & 7) << 4); }
// full 4-bit row swizzle for the h buffer (256B rows, 16-row period)
__device__ __forceinline__ int hswz(int row, int kbyte){ return kbyte ^ ((row & 15) << 4); }

__device__ __forceinline__ bf16x8 lds_frag(const char* s, int row, int rowb, int kbyte){
  return *(const bf16x8*)(s + row * rowb + swz(row, kbyte));
}

__device__ __forceinline__ void copy16(char* dst, const char* __restrict__ src, int bytes){
  for (int o = threadIdx.x * 16; o < bytes; o += blockDim.x * 16)
    *(f32x4*)(dst + o) = *(const f32x4*)(src + o);
}

// ---------------- weight prep: f32 [K][N] -> bf16 transposed swizzled image [n][k] ----------------
// mode 1: permute output-col n -> ((n&7)<<4)|(n>>3)   (thread's 8 C elems = contiguous logical cols)
// mode 3: permute output-col n -> ((n&15)<<4)|(n>>4)  (W1, N=256: 16 contiguous logical hcols/thread)
struct WPrep {
  const float* w[10];
  int Kd[10], Nd[10], off[10], cum[10], mode[10];
};

__global__ void k_wprep(WPrep d, char* img, int total){
  for (int idx = blockIdx.x * blockDim.x + threadIdx.x; idx < total; idx += gridDim.x * blockDim.x){
    int i = 0;
#pragma unroll
    for (int j = 1; j < 10; j++) if (idx >= d.cum[j]) i = j;
    int loc = idx - d.cum[i];
    int K = d.Kd[i], N = d.Nd[i];
    int n = loc / K, k = loc - n * K;
    float val = d.w[i][(size_t)k * N + n];
    int nn = n;
    if (d.mode[i] == 1) nn = ((n & 7) << 4) | (n >> 3);
    if (d.mode[i] == 3) nn = ((n & 15) << 4) | (n >> 4);
    *(bf16_t*)(img + d.off[i] + nn * (K * 2) + swz(nn, k * 2)) = (bf16_t)val;
  }
}

// ---------------- CSR build ----------------
__global__ void k_count(const int* __restrict__ dst, int* __restrict__ cnt){
  int i = blockIdx.x * blockDim.x + threadIdx.x;
  if (i < N_EDGES) atomicAdd(&cnt[dst[i]], 1);
}

__global__ __launch_bounds__(1024) void k_scan(const int* __restrict__ cnt,
                                               int* __restrict__ rowptr, int* __restrict__ wp){
  __shared__ int wsum[16];
  __shared__ int wpre[16];
  __shared__ int scarry;
  const int tid = threadIdx.x, lane = tid & 63, wv = tid >> 6;
  if (tid == 0) scarry = 0;
  for (int base = 0; base < N_NODES; base += 8192){
    int i0 = base + tid * 8;
    int v[8], p[8];
    int tsum = 0;
#pragma unroll
    for (int j = 0; j < 8; j++){
      int idx = i0 + j;
      v[j] = (idx < N_NODES) ? cnt[idx] : 0;
      p[j] = tsum; tsum += v[j];
    }
    int x = tsum;
#pragma unroll
    for (int off = 1; off < 64; off <<= 1){
      int t = __shfl_up(x, off);
      if (lane >= off) x += t;
    }
    if (lane == 63) wsum[wv] = x;
    __syncthreads();
    if (tid == 0){
      int run = scarry;
#pragma unroll
      for (int j = 0; j < 16; j++){ int t = wsum[j]; wpre[j] = run; run += t; }
      scarry = run;
    }
    __syncthreads();
    int texcl = wpre[wv] + x - tsum;
#pragma unroll
    for (int j = 0; j < 8; j++){
      int idx = i0 + j;
      if (idx < N_NODES){ rowptr[idx] = texcl + p[j]; wp[idx] = texcl + p[j]; }
    }
  }
  __syncthreads();
  if (tid == 0) rowptr[N_NODES] = scarry;
}

__global__ void k_fill(const int* __restrict__ dst, int* __restrict__ wp, int* __restrict__ csr){
  int i = blockIdx.x * blockDim.x + threadIdx.x;
  if (i < N_EDGES){
    int p = atomicAdd(&wp[dst[i]], 1);
    csr[p] = i;
  }
}

// ---------------- QKV: [M,128] @ 3x [128,128] -> bf16 outputs (mode-1 weights -> vector stores) ----------------
__global__ __launch_bounds__(512) void k_qkv(
    const float* __restrict__ v, const char* __restrict__ img,
    bf16_t* __restrict__ Q, bf16_t* __restrict__ K, bf16_t* __restrict__ V, int M)
{
  __shared__ __align__(16) char sm[65536];
  char* sX = sm;
  char* sW = sm + 32768;
  const int tid = threadIdx.x, lane = tid & 63, wave = tid >> 6;
  const int r0 = blockIdx.x * 128;
  for (int c = tid; c < 2048; c += 512){
    int row = c >> 4, kc = c & 15, grow = r0 + row;
    float f[8];
    if (grow < M){
      const float4* p = (const float4*)(v + (size_t)grow * DIM + kc * 8);
      float4 u0 = p[0], u1 = p[1];
      f[0]=u0.x; f[1]=u0.y; f[2]=u0.z; f[3]=u0.w;
      f[4]=u1.x; f[5]=u1.y; f[6]=u1.z; f[7]=u1.w;
    } else {
#pragma unroll
      for (int j=0;j<8;j++) f[j] = 0.f;
    }
    bf16x8 o;
#pragma unroll
    for (int j=0;j<8;j++) o[j] = (bf16_t)f[j];
    *(bf16x8*)(sX + row * 256 + swz(row, kc * 16)) = o;
  }
  const int rowA = wave * 16 + (lane & 15);
  const int kb0 = (lane >> 4) * 16;
  const int crow = wave*16 + (lane >> 4)*4;
  const int ccol = lane & 15;
  const f32x4 zero4 = {0.f, 0.f, 0.f, 0.f};
#pragma unroll
  for (int w3 = 0; w3 < 3; w3++){
    __syncthreads();            // staging done / prev GEMM done with sW
    copy16(sW, img + w3 * 32768, 32768);
    __syncthreads();
    f32x4 acc[8];
#pragma unroll
    for (int b=0;b<8;b++) acc[b] = zero4;
#pragma unroll
    for (int ks=0; ks<4; ks++){
      bf16x8 a = lds_frag(sX, rowA, 256, ks*64 + kb0);
#pragma unroll
      for (int nt=0; nt<8; nt++){
        int rn = nt*16 + (lane & 15);
        bf16x8 b = lds_frag(sW, rn, 256, ks*64 + kb0);
        acc[nt] = MFMA(a, b, acc[nt]);
      }
    }
    bf16_t* o = (w3 == 0) ? Q : ((w3 == 1) ? K : V);
    // mode-1 perm: acc[nt] = logical col ccol*8+nt -> one bf16x8 store per row
#pragma unroll
    for (int r=0; r<4; r++){
      int grow = r0 + crow + r;
      if (grow < M){
        bf16x8 t;
#pragma unroll
        for (int nt=0; nt<8; nt++) t[nt] = (bf16_t)acc[nt][r];
        *(bf16x8*)(o + (size_t)grow * DIM + ccol*8) = t;
      }
    }
  }
}

// ---------------- fused edge attention ----------------
// Direct-global A-frags for e (no LDS staging); f32 residual from L2-warm re-read.
__global__ __launch_bounds__(512, 4) void k_edge(
    const float* __restrict__ e,
    const int* __restrict__ src, const int* __restrict__ dst,
    const bf16_t* __restrict__ Qb, const bf16_t* __restrict__ Kb,
    const char* __restrict__ imgWe, const char* __restrict__ imgWo,
    const float* __restrict__ bOe,
    float* __restrict__ e1_pre, float* __restrict__ sv,
    float* __restrict__ stats, int M)
{
  __shared__ __align__(16) char sm[66560];
  char* sW = sm;                          // 32KB: We then WO_e
  char* sX = sm + 32768;                  // 32KB: score
  float* sStats = (float*)(sm + 65536);   // 256 f
  const int tid = threadIdx.x, lane = tid & 63, wave = tid >> 6;
  const int r0 = blockIdx.x * 128;
  const int crow = wave*16 + (lane >> 4)*4;
  const int ccol = lane & 15;
  const int rowA = wave * 16 + (lane & 15);
  const int q = lane >> 4;
  const int kb0 = q * 16;
  // prefetch K[src]/Q[dst] fragments (in flight through We copy + conversion)
  bf16x8 Kg[4], Qg[4];
#pragma unroll
  for (int r=0;r<4;r++){
    int ed = r0 + crow + r; if (ed >= M) ed = M - 1;
    int sn = src[ed], dn = dst[ed];
    Kg[r] = *(const bf16x8*)(Kb + (size_t)sn * DIM + ccol * 8);
    Qg[r] = *(const bf16x8*)(Qb + (size_t)dn * DIM + ccol * 8);
  }
  // direct A: full e row rowA (clamped; garbage rows are epilogue-guarded)
  int grA = r0 + rowA; if (grA >= M) grA = M - 1;
  const f32x4* epA = (const f32x4*)(e + (size_t)grA * DIM);
  f32x4 ea[8];
#pragma unroll
  for (int ks=0; ks<4; ks++){
    ea[2*ks]   = epA[ks*8 + q*2];
    ea[2*ks+1] = epA[ks*8 + q*2 + 1];
  }
  copy16(sW, imgWe, 32768);
  if (tid < 256) sStats[tid] = 0.f;
  bf16x8 eAb[4];
#pragma unroll
  for (int ks=0; ks<4; ks++){
#pragma unroll
    for (int j=0;j<4;j++){
      eAb[ks][j]   = (bf16_t)ea[2*ks][j];
      eAb[ks][4+j] = (bf16_t)ea[2*ks+1][j];
    }
  }
  __syncthreads();   // B1: We staged
  const f32x4 zero4 = {0.f,0.f,0.f,0.f};
  // issue WO loads (land during GEMM1)
  f32x4 wbuf[4];
#pragma unroll
  for (int i=0;i<4;i++) wbuf[i] = *(const f32x4*)(imgWo + tid*16 + i*8192);
  f32x4 pe[8];
#pragma unroll
  for (int i=0;i<8;i++) pe[i] = zero4;
#pragma unroll
  for (int ks=0; ks<4; ks++){
#pragma unroll
    for (int nt=0; nt<8; nt++){
      int rn = nt*16 + (lane & 15);
      bf16x8 b = lds_frag(sW, rn, 256, ks*64 + kb0);
      pe[nt] = MFMA(eAb[ks], b, pe[nt]);
    }
  }
  __syncthreads();   // B2: all waves done reading We
  // write WO_e into sW (reg-staged); issue f32 residual loads (L2-warm tile lines)
#pragma unroll
  for (int i=0;i<4;i++) *(f32x4*)(sW + tid*16 + i*8192) = wbuf[i];
  f32x4 er[8];
#pragma unroll
  for (int r=0;r<4;r++){
    int gr = r0 + crow + r; if (gr >= M) gr = M - 1;
    const f32x4* rp = (const f32x4*)(e + (size_t)gr*DIM + ccol*8);
    er[2*r]   = rp[0];
    er[2*r+1] = rp[1];
  }
  // score: logical col ccol*8+nt -> one bf16x8 per row into sX
#pragma unroll
  for (int r=0;r<4;r++){
    int row = crow + r;
    bf16x8 t;
    float hsum = 0.f;
#pragma unroll
    for (int nt=0; nt<8; nt++){
      float sc = pe[nt][r] * 0.25f * (float)Kg[r][nt] * (float)Qg[r][nt];
      t[nt] = (bf16_t)sc;
      hsum += sc;
    }
    *(bf16x8*)(sX + row*256 + swz(row, ccol*16)) = t;
    float ts = hsum + __shfl_xor(hsum, 1);   // pair covers the full 16-col head
    int ed = r0 + row;
    if (!(ccol & 1) && ed < M)
      sv[(size_t)ed*8 + (ccol >> 1)] = __expf(fminf(5.f, fmaxf(-5.f, ts)));
  }
  __syncthreads();   // B3: score + WO ready
  // GEMM2: e_attn @ WO_e
  f32x4 a2[8];
#pragma unroll
  for (int i=0;i<8;i++) a2[i] = zero4;
#pragma unroll
  for (int ks=0; ks<4; ks++){
    bf16x8 a = lds_frag(sX, rowA, 256, ks*64 + kb0);
#pragma unroll
    for (int nt=0; nt<8; nt++){
      int rn = nt*16 + (lane & 15);
      bf16x8 b = lds_frag(sW, rn, 256, ks*64 + kb0);
      a2[nt] = MFMA(a, b, a2[nt]);
    }
  }
  // epilogue: f32 residual from regs, vectorized stores
  float4 bo0 = *(const float4*)(bOe + ccol*8);
  float4 bo1 = *(const float4*)(bOe + ccol*8 + 4);
  float s1[8], s2[8];
#pragma unroll
  for (int j=0;j<8;j++){ s1[j]=0.f; s2[j]=0.f; }
#pragma unroll
  for (int r=0; r<4; r++){
    int ed = r0 + crow + r;
    float val[8];
    if (ed < M){
      val[0]=a2[0][r]+er[2*r][0]+bo0.x; val[1]=a2[1][r]+er[2*r][1]+bo0.y;
      val[2]=a2[2][r]+er[2*r][2]+bo0.z; val[3]=a2[3][r]+er[2*r][3]+bo0.w;
      val[4]=a2[4][r]+er[2*r+1][0]+bo1.x; val[5]=a2[5][r]+er[2*r+1][1]+bo1.y;
      val[6]=a2[6][r]+er[2*r+1][2]+bo1.z; val[7]=a2[7][r]+er[2*r+1][3]+bo1.w;
      float4 o0 = {val[0],val[1],val[2],val[3]};
      float4 o1 = {val[4],val[5],val[6],val[7]};
      float4* op = (float4*)(e1_pre + (size_t)ed*DIM + ccol*8);
      op[0] = o0; op[1] = o1;
    } else {
#pragma unroll
      for (int j=0;j<8;j++) val[j]=0.f;
    }
#pragma unroll
    for (int j=0;j<8;j++){ s1[j] += val[j]; s2[j] += val[j]*val[j]; }
  }
#pragma unroll
  for (int j=0;j<8;j++){
    s1[j] += __shfl_xor(s1[j], 16); s1[j] += __shfl_xor(s1[j], 32);
    s2[j] += __shfl_xor(s2[j], 16); s2[j] += __shfl_xor(s2[j], 32);
  }
  if (lane < 16){
#pragma unroll
    for (int j=0;j<8;j++){
      atomicAdd(&sStats[ccol*8 + j], s1[j]);
      atomicAdd(&sStats[128 + ccol*8 + j], s2[j]);
    }
  }
  __syncthreads();
  if (tid < 256) unsafeAtomicAdd(&stats[tid], sStats[tid]);
}

// ---------------- aggregation: one wave per node, CSR walk, 4-deep pipelined ----------------
__global__ __launch_bounds__(512) void k_agg(
    const int* __restrict__ rowptr, const int* __restrict__ csr,
    const int* __restrict__ src, const float* __restrict__ envl,
    const float* __restrict__ sv, const bf16_t* __restrict__ V,
    bf16_t* __restrict__ vAttn, int M)
{
  const int wave = threadIdx.x >> 6, lane = threadIdx.x & 63;
  const int n = blockIdx.x * 8 + wave;
  if (n >= M) return;
  const int beg = rowptr[n], end = rowptr[n + 1];
  const int h = lane >> 3;           // head of cols (2*lane, 2*lane+1)
  float ax = 0.f, ay = 0.f, zacc = 0.f;
  int i = beg;
  for (; i + 4 <= end; i += 4){
    int e0 = csr[i], e1 = csr[i+1], e2 = csr[i+2], e3 = csr[i+3];
    int sn0 = src[e0], sn1 = src[e1], sn2 = src[e2], sn3 = src[e3];
    float sv0 = sv[(size_t)e0*8 + h], sv1 = sv[(size_t)e1*8 + h];
    float sv2 = sv[(size_t)e2*8 + h], sv3 = sv[(size_t)e3*8 + h];
    float n0 = envl[e0], n1 = envl[e1], n2 = envl[e2], n3 = envl[e3];
    bf16x2 a0 = *(const bf16x2*)(V + (size_t)sn0 * DIM + lane * 2);
    bf16x2 a1 = *(const bf16x2*)(V + (size_t)sn1 * DIM + lane * 2);
    bf16x2 a2v = *(const bf16x2*)(V + (size_t)sn2 * DIM + lane * 2);
    bf16x2 a3 = *(const bf16x2*)(V + (size_t)sn3 * DIM + lane * 2);
    float w0 = n0*sv0, w1 = n1*sv1, w2 = n2*sv2, w3 = n3*sv3;
    ax += (float)a0[0]*w0 + (float)a1[0]*w1 + (float)a2v[0]*w2 + (float)a3[0]*w3;
    ay += (float)a0[1]*w0 + (float)a1[1]*w1 + (float)a2v[1]*w2 + (float)a3[1]*w3;
    zacc += sv0 + sv1 + sv2 + sv3;
  }
  for (; i < end; i++){
    int eid = csr[i];
    int sn = src[eid];
    float s = sv[(size_t)eid * 8 + h];
    float env = envl[eid];
    const bf16x2 vv = *(const bf16x2*)(V + (size_t)sn * DIM + lane * 2);
    float w = env * s;
    ax += (float)vv[0] * w; ay += (float)vv[1] * w;
    zacc += s;
  }
  float inv = 1.f / (zacc + 1e-6f);
  bf16x2 o; o[0] = (bf16_t)(ax * inv); o[1] = (bf16_t)(ay * inv);
  *(bf16x2*)(vAttn + (size_t)n * DIM + lane * 2) = o;
}

// ---------------- node: v1_pre = v + v_attn@WO_v + bOv; stats (WO_v mode-1) ----------------
__global__ __launch_bounds__(512) void k_nodeout(
    const bf16_t* __restrict__ vAttn, const float* __restrict__ v,
    const char* __restrict__ imgWo, const float* __restrict__ bOv,
    float* __restrict__ v1_pre, float* __restrict__ stats, int M)
{
  __shared__ __align__(16) char sm[66560];
  char* sW = sm;
  char* sX = sm + 32768;
  float* sStats = (float*)(sm + 65536);
  const int tid = threadIdx.x, lane = tid & 63, wave = tid >> 6;
  const int r0 = blockIdx.x * 128;
  copy16(sW, imgWo, 32768);
  if (tid < 256) sStats[tid] = 0.f;
  for (int c = tid; c < 2048; c += 512){
    int row = c >> 4, kc = c & 15, grow = r0 + row;
    bf16x8 o;
    if (grow < M){
      o = *(const bf16x8*)(vAttn + (size_t)grow * DIM + kc * 8);
    } else {
#pragma unroll
      for (int j=0;j<8;j++) o[j] = (bf16_t)0.f;
    }
    *(bf16x8*)(sX + row*256 + swz(row, kc*16)) = o;
  }
  __syncthreads();
  const int rowA = wave*16 + (lane & 15);
  const int kb0 = (lane >> 4)*16;
  const f32x4 zero4 = {0.f,0.f,0.f,0.f};
  f32x4 acc[8];
#pragma unroll
  for (int i=0;i<8;i++) acc[i]=zero4;
#pragma unroll
  for (int ks=0;ks<4;ks++){
    bf16x8 a = lds_frag(sX, rowA, 256, ks*64+kb0);
#pragma unroll
    for (int nt=0;nt<8;nt++){
      int rn = nt*16 + (lane&15);
      bf16x8 b = lds_frag(sW, rn, 256, ks*64+kb0);
      acc[nt] = MFMA(a,b,acc[nt]);
    }
  }
  const int crow = wave*16 + (lane>>4)*4;
  const int ccol = lane & 15;
  float4 bo0 = *(const float4*)(bOv + ccol*8);
  float4 bo1 = *(const float4*)(bOv + ccol*8 + 4);
  float s1[8], s2[8];
#pragma unroll
  for (int j=0;j<8;j++){ s1[j]=0.f; s2[j]=0.f; }
#pragma unroll
  for (int r=0;r<4;r++){
    int grow = r0 + crow + r;
    float val[8];
    if (grow < M){
      const float4* vp = (const float4*)(v + (size_t)grow*DIM + ccol*8);
      float4 v0 = vp[0], v1 = vp[1];
      val[0]=acc[0][r]+v0.x+bo0.x; val[1]=acc[1][r]+v0.y+bo0.y;
      val[2]=acc[2][r]+v0.z+bo0.z; val[3]=acc[3][r]+v0.w+bo0.w;
      val[4]=acc[4][r]+v1.x+bo1.x; val[5]=acc[5][r]+v1.y+bo1.y;
      val[6]=acc[6][r]+v1.z+bo1.z; val[7]=acc[7][r]+v1.w+bo1.w;
      float4 o0 = {val[0],val[1],val[2],val[3]};
      float4 o1 = {val[4],val[5],val[6],val[7]};
      float4* op = (float4*)(v1_pre + (size_t)grow*DIM + ccol*8);
      op[0] = o0; op[1] = o1;
    } else {
#pragma unroll
      for (int j=0;j<8;j++) val[j]=0.f;
    }
#pragma unroll
    for (int j=0;j<8;j++){ s1[j] += val[j]; s2[j] += val[j]*val[j]; }
  }
#pragma unroll
  for (int j=0;j<8;j++){
    s1[j] += __shfl_xor(s1[j], 16); s1[j] += __shfl_xor(s1[j], 32);
    s2[j] += __shfl_xor(s2[j], 16); s2[j] += __shfl_xor(s2[j], 32);
  }
  if (lane < 16){
#pragma unroll
    for (int j=0;j<8;j++){
      atomicAdd(&sStats[ccol*8 + j], s1[j]);
      atomicAdd(&sStats[128 + ccol*8 + j], s2[j]);
    }
  }
  __syncthreads();
  if (tid < 256) unsafeAtomicAdd(&stats[tid], sStats[tid]);
}

// ---------------- fused FFN ----------------
// Direct-global A-frags with inline BN (held in regs for both GEMM1 passes);
// sA holds only h (hswz); W1 mode-3, W2 mode-1; bf16 x1 residual in regs.
__global__ __launch_bounds__(512, 4) void k_ffn(
    float* __restrict__ xio, const float* __restrict__ ss1,
    const char* __restrict__ img1, const float* __restrict__ b1,
    const char* __restrict__ img2, const float* __restrict__ b2,
    float* __restrict__ stats2, int M)
{
  __shared__ __align__(16) char sm[66560];
  char* sA = sm;           // h halves (hswz layout)
  char* sB = sm + 32768;   // W1h0, W1h1, W2k0, W2k1
  float* sStats = (float*)(sm + 65536);
  const int tid = threadIdx.x, lane = tid & 63, wave = tid >> 6;
  const int r0 = blockIdx.x * 128;
  const int rowA = wave*16 + (lane & 15);
  const int q = lane >> 4;
  const int kb0 = q * 16;
  const int crow = wave*16 + q*4;
  const int ccol = lane & 15;
  const f32x4 zero4 = {0.f,0.f,0.f,0.f};

  // BN scale/shift for this thread's 8 contiguous epilogue cols
  float4 sc0 = *(const float4*)(ss1 + ccol*8);
  float4 sc1 = *(const float4*)(ss1 + ccol*8 + 4);
  float4 sh0 = *(const float4*)(ss1 + 128 + ccol*8);
  float4 sh1 = *(const float4*)(ss1 + 128 + ccol*8 + 4);
  // biases for this thread's 16 contiguous logical hcols
  const float4* bq = (const float4*)(b1 + ccol * 16);
  float4 bq0 = bq[0], bq1 = bq[1], bq2 = bq[2], bq3 = bq[3];

  // phase 1: W1h0 -> LDS; direct A row load + BN; footprint residual
  copy16(sB, img1, 32768);
  if (tid < 256) sStats[tid] = 0.f;
  int grA = r0 + rowA; if (grA >= M) grA = M - 1;
  const f32x4* xp = (const f32x4*)(xio + (size_t)grA * DIM);
  f32x4 xa[8];
#pragma unroll
  for (int ks=0; ks<4; ks++){
    xa[2*ks]   = xp[ks*8 + q*2];
    xa[2*ks+1] = xp[ks*8 + q*2 + 1];
  }
  bf16x8 xres[4];
#pragma unroll
  for (int r = 0; r < 4; r++){
    int grow = r0 + crow + r;
    bf16x8 o;
    if (grow < M){
      const f32x4* p = (const f32x4*)(xio + (size_t)grow*DIM + ccol*8);
      f32x4 u0 = p[0], u1 = p[1];
      o[0]=(bf16_t)(u0[0]*sc0.x+sh0.x); o[1]=(bf16_t)(u0[1]*sc0.y+sh0.y);
      o[2]=(bf16_t)(u0[2]*sc0.z+sh0.z); o[3]=(bf16_t)(u0[3]*sc0.w+sh0.w);
      o[4]=(bf16_t)(u1[0]*sc1.x+sh1.x); o[5]=(bf16_t)(u1[1]*sc1.y+sh1.y);
      o[6]=(bf16_t)(u1[2]*sc1.z+sh1.z); o[7]=(bf16_t)(u1[3]*sc1.w+sh1.w);
    } else {
#pragma unroll
      for (int j=0;j<8;j++) o[j]=(bf16_t)0.f;
    }
    xres[r] = o;
  }
  // BN on A frags (ss is L1-resident)
  bf16x8 xAb[4];
#pragma unroll
  for (int ks=0; ks<4; ks++){
    const f32x4* sp = (const f32x4*)(ss1 + ks*32 + q*8);
    const f32x4* hp = (const f32x4*)(ss1 + 128 + ks*32 + q*8);
    f32x4 s0 = sp[0], s1v = sp[1], h0 = hp[0], h1 = hp[1];
#pragma unroll
    for (int j=0;j<4;j++){
      xAb[ks][j]   = (bf16_t)(xa[2*ks][j]  *s0[j]  + h0[j]);
      xAb[ks][4+j] = (bf16_t)(xa[2*ks+1][j]*s1v[j] + h1[j]);
    }
  }
  __syncthreads();  // B1: W1h0 ready

  bf16x8 hreg[8];   // [r] = half0 hcols (nt 0..7), [4+r] = half1 (nt 8..15)
  f32x4 wbuf[4];    // reg-staged next weight chunk

  // phase 2: GEMM1a (+ issue W1 half1 loads)
#pragma unroll
  for (int i=0;i<4;i++) wbuf[i] = *(const f32x4*)(img1 + 32768 + tid*16 + i*8192);
  {
    f32x4 acc[8];
#pragma unroll
    for (int i=0;i<8;i++) acc[i]=zero4;
#pragma unroll
    for (int ks=0;ks<4;ks++){
#pragma unroll
      for (int nt=0;nt<8;nt++){
        int rn = nt*16 + (lane&15);
        bf16x8 b = lds_frag(sB, rn, 256, ks*64+kb0);
        acc[nt] = MFMA(xAb[ks], b, acc[nt]);
      }
    }
#pragma unroll
    for (int r=0;r<4;r++){
      bf16x8 t;
      t[0]=(bf16_t)fmaxf(acc[0][r]+bq0.x,0.f); t[1]=(bf16_t)fmaxf(acc[1][r]+bq0.y,0.f);
      t[2]=(bf16_t)fmaxf(acc[2][r]+bq0.z,0.f); t[3]=(bf16_t)fmaxf(acc[3][r]+bq0.w,0.f);
      t[4]=(bf16_t)fmaxf(acc[4][r]+bq1.x,0.f); t[5]=(bf16_t)fmaxf(acc[5][r]+bq1.y,0.f);
      t[6]=(bf16_t)fmaxf(acc[6][r]+bq1.z,0.f); t[7]=(bf16_t)fmaxf(acc[7][r]+bq1.w,0.f);
      hreg[r] = t;
    }
  }
  __syncthreads();
  // phase 3: write W1 half1
#pragma unroll
  for (int i=0;i<4;i++) *(f32x4*)(sB + tid*16 + i*8192) = wbuf[i];
  __syncthreads();
  // phase 4: GEMM1b (+ issue W2 k-half0 loads)
#pragma unroll
  for (int i=0;i<4;i++){
    int o = tid*16 + i*8192;
    wbuf[i] = *(const f32x4*)(img2 + (o >> 8)*512 + (o & 255));
  }
  {
    f32x4 acc[8];
#pragma unroll
    for (int i=0;i<8;i++) acc[i]=zero4;
#pragma unroll
    for (int ks=0;ks<4;ks++){
#pragma unroll
      for (int nt=0;nt<8;nt++){
        int rn = nt*16 + (lane&15);
        bf16x8 b = lds_frag(sB, rn, 256, ks*64+kb0);
        acc[nt] = MFMA(xAb[ks], b, acc[nt]);
      }
    }
#pragma unroll
    for (int r=0;r<4;r++){
      bf16x8 t;
      t[0]=(bf16_t)fmaxf(acc[0][r]+bq2.x,0.f); t[1]=(bf16_t)fmaxf(acc[1][r]+bq2.y,0.f);
      t[2]=(bf16_t)fmaxf(acc[2][r]+bq2.z,0.f); t[3]=(bf16_t)fmaxf(acc[3][r]+bq2.w,0.f);
      t[4]=(bf16_t)fmaxf(acc[4][r]+bq3.x,0.f); t[5]=(bf16_t)fmaxf(acc[5][r]+bq3.y,0.f);
      t[6]=(bf16_t)fmaxf(acc[6][r]+bq3.z,0.f); t[7]=(bf16_t)fmaxf(acc[7][r]+bq3.w,0.f);
      hreg[4+r] = t;
    }
  }
  __syncthreads();   // sB free

  f32x4 o2[8];
#pragma unroll
  for (int i=0;i<8;i++) o2[i]=zero4;

#pragma unroll
  for (int half = 0; half < 2; half++){
    // write h k-half into sA (hswz layout, rows 256B of 128 hcols)
    if ((ccol >> 3) == half){
      int cb = (ccol & 7) * 32;
#pragma unroll
      for (int r=0;r<4;r++){
        int row = crow + r;
        *(bf16x8*)(sA + row*256 + hswz(row, cb))      = hreg[r];
        *(bf16x8*)(sA + row*256 + hswz(row, cb + 16)) = hreg[4+r];
      }
    }
    // write W2 k-half (reg-staged)
#pragma unroll
    for (int i=0;i<4;i++) *(f32x4*)(sB + tid*16 + i*8192) = wbuf[i];
    __syncthreads();
    // issue loads for W2 k-half1 during GEMM2a
    if (half == 0){
#pragma unroll
      for (int i=0;i<4;i++){
        int o = tid*16 + i*8192;
        wbuf[i] = *(const f32x4*)(img2 + (o >> 8)*512 + 256 + (o & 255));
      }
    }
    // GEMM2 over this k-half
#pragma unroll
    for (int ks=0;ks<4;ks++){
      const char* ap = sA + rowA*256 + hswz(rowA, ks*64+kb0);
      bf16x8 a = *(const bf16x8*)ap;
#pragma unroll
      for (int nt=0;nt<8;nt++){
        int rn = nt*16 + (lane&15);
        bf16x8 b = lds_frag(sB, rn, 256, ks*64+kb0);
        o2[nt] = MFMA(a,b,o2[nt]);
      }
    }
    __syncthreads();
  }

  // epilogue: residual from regs (x1 bf16), vectorized stores
  float4 b20 = *(const float4*)(b2 + ccol*8);
  float4 b21 = *(const float4*)(b2 + ccol*8 + 4);
  float s1[8], s2[8];
#pragma unroll
  for (int j=0;j<8;j++){ s1[j]=0.f; s2[j]=0.f; }
#pragma unroll
  for (int r=0;r<4;r++){
    int grow = r0 + crow + r;
    float val[8];
    val[0]=(float)xres[r][0]+o2[0][r]+b20.x; val[1]=(float)xres[r][1]+o2[1][r]+b20.y;
    val[2]=(float)xres[r][2]+o2[2][r]+b20.z; val[3]=(float)xres[r][3]+o2[3][r]+b20.w;
    val[4]=(float)xres[r][4]+o2[4][r]+b21.x; val[5]=(float)xres[r][5]+o2[5][r]+b21.y;
    val[6]=(float)xres[r][6]+o2[6][r]+b21.z; val[7]=(float)xres[r][7]+o2[7][r]+b21.w;
    if (grow < M){
      float4 o0 = {val[0],val[1],val[2],val[3]};
      float4 o1 = {val[4],val[5],val[6],val[7]};
      float4* op = (float4*)(xio + (size_t)grow*DIM + ccol*8);
      op[0] = o0; op[1] = o1;
    } else {
#pragma unroll
      for (int j=0;j<8;j++) val[j]=0.f;
    }
#pragma unroll
    for (int j=0;j<8;j++){ s1[j] += val[j]; s2[j] += val[j]*val[j]; }
  }
#pragma unroll
  for (int j=0;j<8;j++){
    s1[j] += __shfl_xor(s1[j], 16); s1[j] += __shfl_xor(s1[j], 32);
    s2[j] += __shfl_xor(s2[j], 16); s2[j] += __shfl_xor(s2[j], 32);
  }
  if (lane < 16){
#pragma unroll
    for (int j=0;j<8;j++){
      atomicAdd(&sStats[ccol*8 + j], s1[j]);
      atomicAdd(&sStats[128 + ccol*8 + j], s2[j]);
    }
  }
  __syncthreads();
  if (tid < 256) unsafeAtomicAdd(&stats2[tid], sStats[tid]);
}

// ---------------- stats -> scale/shift ----------------
struct FinArgs { const float* st; const float* g; const float* b; float* ss; float invM; };

__global__ void k_finstats(FinArgs a0, FinArgs a1){
  FinArgs a = (blockIdx.x == 0) ? a0 : a1;
  int c = threadIdx.x;
  float mean = a.st[c] * a.invM;
  float var  = a.st[128 + c] * a.invM - mean * mean;
  float scl  = a.g[c] * rsqrtf(var + 1e-5f);
  a.ss[c] = scl;
  a.ss[128 + c] = a.b[c] - mean * scl;
}

// ---------------- in-place normalize (v and e fused in one launch) ----------------
__global__ void k_norm2(float* __restrict__ xv, float* __restrict__ xe,
                        const float* __restrict__ ssv, const float* __restrict__ sse,
                        long long nv4, long long ne4){
  long long total = nv4 + ne4;
  for (long long i = (long long)blockIdx.x * blockDim.x + threadIdx.x; i < total;
       i += (long long)gridDim.x * blockDim.x){
    bool isv = i < nv4;
    float* x = isv ? xv : xe;
    const float* ss = isv ? ssv : sse;
    long long j = isv ? i : i - nv4;
    float4* p = (float4*)x + j;
    float4 t = *p;
    int c0 = (int)((j * 4) & 127);
    t.x = t.x * ss[c0]     + ss[128 + c0];
    t.y = t.y * ss[c0 + 1] + ss[128 + c0 + 1];
    t.z = t.z * ss[c0 + 2] + ss[128 + c0 + 2];
    t.w = t.w * ss[c0 + 3] + ss[128 + c0 + 3];
    *p = t;
  }
}

extern "C" void kernel_launch(void* const* d_in, const int* in_sizes, int n_in,
                              void* d_out, int out_size, void* d_ws, size_t ws_size,
                              hipStream_t stream)
{
  const float* v    = (const float*)d_in[0];
  const float* e    = (const float*)d_in[1];
  const float* envl = (const float*)d_in[2];
  const int*   src  = (const int*)d_in[3];
  const int*   dst  = (const int*)d_in[4];
  const float* bOv  = (const float*)d_in[10];
  const float* bOe  = (const float*)d_in[12];
  const float* g1v  = (const float*)d_in[13];
  const float* b1vn = (const float*)d_in[14];
  const float* g1e  = (const float*)d_in[15];
  const float* b1en = (const float*)d_in[16];
  const float* g2v  = (const float*)d_in[17];
  const float* b2vn = (const float*)d_in[18];
  const float* g2e  = (const float*)d_in[19];
  const float* b2en = (const float*)d_in[20];
  const float* b1vf = (const float*)d_in[22];
  const float* b2vf = (const float*)d_in[24];
  const float* b1ef = (const float*)d_in[26];
  const float* b2ef = (const float*)d_in[28];

  float* out_v = (float*)d_out;
  float* out_e = out_v + (size_t)N_NODES * DIM;

  char* ws = (char*)d_ws;
  const size_t IMG_OFF = 0;                        // 458752 B of bf16 weight images
  const size_t QB_OFF  = 458752;                   // bf16 Q  (N*128*2 = 12.8MB)
  const size_t KB_OFF  = QB_OFF  + 12800000;       // bf16 K
  const size_t VB_OFF  = KB_OFF  + 12800000;       // bf16 V
  const size_t VA_OFF  = VB_OFF  + 12800000;       // bf16 vAttn
  const size_t SV_OFF  = VA_OFF  + 12800000;       // s per edge per head: E*8*4 = 16MB
  const size_t CSR_OFF = SV_OFF  + 16000000;       // E ints
  const size_t RP_OFF  = CSR_OFF + 2000000;        // N+1 ints
  const size_t WP_OFF  = RP_OFF  + 200016;         // N ints
  const size_t CNT_OFF = WP_OFF  + 200000;         // N ints (memset 0)
  const size_t ST_OFF  = CNT_OFF + 200000;         // 1024 f (memset 0)
  const size_t SS_OFF  = ST_OFF  + 4096;           // 1024 f

  char*   img   = ws + IMG_OFF;
  bf16_t* Qb    = (bf16_t*)(ws + QB_OFF);
  bf16_t* Kb    = (bf16_t*)(ws + KB_OFF);
  bf16_t* Vb    = (bf16_t*)(ws + VB_OFF);
  bf16_t* vAttn = (bf16_t*)(ws + VA_OFF);
  float*  svp   = (float*)(ws + SV_OFF);
  int*    csr   = (int*)(ws + CSR_OFF);
  int*    rowp  = (int*)(ws + RP_OFF);
  int*    wpp   = (int*)(ws + WP_OFF);
  int*    cnt   = (int*)(ws + CNT_OFF);
  float*  st    = (float*)(ws + ST_OFF);
  float*  ssb   = (float*)(ws + SS_OFF);
  float* st_e1 = st;        float* st_v1 = st + 256;
  float* st_v2 = st + 512;  float* st_e2 = st + 768;
  float* ss_v1 = ssb;       float* ss_e1 = ssb + 256;
  float* ss_v2 = ssb + 512; float* ss_e2 = ssb + 768;

  // zero counters + stats (contiguous)
  (void)hipMemsetAsync(ws + CNT_OFF, 0, 200000 + 4096, stream);

  WPrep wp;
  const int wid[10]   = {5,6,7,8,9,11,21,23,25,27};
  const int Ks[10]    = {128,128,128,128,128,128,128,256,128,256};
  const int Ns[10]    = {128,128,128,128,128,128,256,128,256,128};
  const int modes[10] = {1,1,1,1,1,1,3,1,3,1};   // QKV/We/WO_*/W2: p8 n-perm; W1: p16 n-perm
  int cum = 0, off = 0;
  for (int i = 0; i < 10; i++){
    wp.w[i] = (const float*)d_in[wid[i]];
    wp.Kd[i] = Ks[i]; wp.Nd[i] = Ns[i];
    wp.off[i] = off; wp.cum[i] = cum; wp.mode[i] = modes[i];
    off += Ks[i]*Ns[i]*2; cum += Ks[i]*Ns[i];
  }
  k_wprep<<<896, 256, 0, stream>>>(wp, img, cum);

  // CSR build (independent of QKV)
  k_count<<<1954, 256, 0, stream>>>(dst, cnt);
  k_scan<<<1, 1024, 0, stream>>>(cnt, rowp, wpp);
  k_fill<<<1954, 256, 0, stream>>>(dst, wpp, csr);

  k_qkv<<<391, 512, 0, stream>>>(v, img, Qb, Kb, Vb, N_NODES);

  k_edge<<<3907, 512, 0, stream>>>(e, src, dst, Qb, Kb,
                                   img + 98304 /*We*/, img + 163840 /*WO_e*/, bOe,
                                   out_e, svp, st_e1, N_EDGES);

  k_agg<<<6250, 512, 0, stream>>>(rowp, csr, src, envl, svp, Vb, vAttn, N_NODES);

  k_nodeout<<<391, 512, 0, stream>>>(vAttn, v, img + 131072 /*WO_v*/, bOv,
                                     out_v, st_v1, N_NODES);

  {
    FinArgs fv{st_v1, g1v, b1vn, ss_v1, 1.f / N_NODES};
    FinArgs fe{st_e1, g1e, b1en, ss_e1, 1.f / N_EDGES};
    k_finstats<<<2, 128, 0, stream>>>(fv, fe);
  }

  k_ffn<<<391, 512, 0, stream>>>(out_v, ss_v1, img + 196608 /*W1v*/, b1vf,
                                 img + 262144 /*W2v*/, b2vf, st_v2, N_NODES);
  k_ffn<<<3907, 512, 0, stream>>>(out_e, ss_e1, img + 327680 /*W1e*/, b1ef,
                                  img + 393216 /*W2e*/, b2ef, st_e2, N_EDGES);

  {
    FinArgs fv{st_v2, g2v, b2vn, ss_v2, 1.f / N_NODES};
    FinArgs fe{st_e2, g2e, b2en, ss_e2, 1.f / N_EDGES};
    k_finstats<<<2, 128, 0, stream>>>(fv, fe);
  }

  k_norm2<<<6144, 256, 0, stream>>>(out_v, out_e, ss_v2, ss_e2,
                                    (long long)(N_NODES) * DIM / 4,
                                    (long long)(N_EDGES) * DIM / 4);
}

// Round 8
// 723.936 us; speedup vs baseline: 1.2077x; 1.1104x over previous
//
#include <hip/hip_runtime.h>
#include <hip/hip_bf16.h>

#define N_NODES 50000
#define N_EDGES 500000
#define DIM 128
// bf16 row-local intermediates: row i occupies first 256B of the 512B f32 row slot
#define RSTRIDE 256   // elements (bf16) per row slot

typedef __bf16 bf16_t;
typedef __bf16 bf16x8 __attribute__((ext_vector_type(8)));
typedef __bf16 bf16x2 __attribute__((ext_vector_type(2)));
typedef float f32x4 __attribute__((ext_vector_type(4)));

#define MFMA(a,b,c) __builtin_amdgcn_mfma_f32_16x16x32_bf16((a),(b),(c),0,0,0)

// XOR swizzle (guide G4): kills 32-way bank conflicts for 256B/512B-stride rows
__device__ __forceinline__ int swz(int row, int kbyte){ return kbyte ^ ((row & 7) << 4); }
// full 4-bit row swizzle for the h buffer (256B rows, 16-row period)
__device__ __forceinline__ int hswz(int row, int kbyte){ return kbyte ^ ((row & 15) << 4); }

__device__ __forceinline__ bf16x8 lds_frag(const char* s, int row, int rowb, int kbyte){
  return *(const bf16x8*)(s + row * rowb + swz(row, kbyte));
}

__device__ __forceinline__ void copy16(char* dst, const char* __restrict__ src, int bytes){
  for (int o = threadIdx.x * 16; o < bytes; o += blockDim.x * 16)
    *(f32x4*)(dst + o) = *(const f32x4*)(src + o);
}

// ---------------- weight prep: f32 [K][N] -> bf16 transposed swizzled image [n][k] ----------------
// mode 1: permute output-col n -> ((n&7)<<4)|(n>>3)   (thread's 8 C elems = contiguous logical cols)
// mode 3: permute output-col n -> ((n&15)<<4)|(n>>4)  (W1, N=256: 16 contiguous logical hcols/thread)
struct WPrep {
  const float* w[10];
  int Kd[10], Nd[10], off[10], cum[10], mode[10];
};

__global__ void k_wprep(WPrep d, char* img, int total){
  for (int idx = blockIdx.x * blockDim.x + threadIdx.x; idx < total; idx += gridDim.x * blockDim.x){
    int i = 0;
#pragma unroll
    for (int j = 1; j < 10; j++) if (idx >= d.cum[j]) i = j;
    int loc = idx - d.cum[i];
    int K = d.Kd[i], N = d.Nd[i];
    int n = loc / K, k = loc - n * K;
    float val = d.w[i][(size_t)k * N + n];
    int nn = n;
    if (d.mode[i] == 1) nn = ((n & 7) << 4) | (n >> 3);
    if (d.mode[i] == 3) nn = ((n & 15) << 4) | (n >> 4);
    *(bf16_t*)(img + d.off[i] + nn * (K * 2) + swz(nn, k * 2)) = (bf16_t)val;
  }
}

// ---------------- CSR build ----------------
__global__ void k_count(const int* __restrict__ dst, int* __restrict__ cnt){
  int i = blockIdx.x * blockDim.x + threadIdx.x;
  if (i < N_EDGES) atomicAdd(&cnt[dst[i]], 1);
}

__global__ __launch_bounds__(1024) void k_scan(const int* __restrict__ cnt,
                                               int* __restrict__ rowptr, int* __restrict__ wp){
  __shared__ int wsum[16];
  __shared__ int wpre[16];
  __shared__ int scarry;
  const int tid = threadIdx.x, lane = tid & 63, wv = tid >> 6;
  if (tid == 0) scarry = 0;
  for (int base = 0; base < N_NODES; base += 8192){
    int i0 = base + tid * 8;
    int v[8], p[8];
    int tsum = 0;
#pragma unroll
    for (int j = 0; j < 8; j++){
      int idx = i0 + j;
      v[j] = (idx < N_NODES) ? cnt[idx] : 0;
      p[j] = tsum; tsum += v[j];
    }
    int x = tsum;
#pragma unroll
    for (int off = 1; off < 64; off <<= 1){
      int t = __shfl_up(x, off);
      if (lane >= off) x += t;
    }
    if (lane == 63) wsum[wv] = x;
    __syncthreads();
    if (tid == 0){
      int run = scarry;
#pragma unroll
      for (int j = 0; j < 16; j++){ int t = wsum[j]; wpre[j] = run; run += t; }
      scarry = run;
    }
    __syncthreads();
    int texcl = wpre[wv] + x - tsum;
#pragma unroll
    for (int j = 0; j < 8; j++){
      int idx = i0 + j;
      if (idx < N_NODES){ rowptr[idx] = texcl + p[j]; wp[idx] = texcl + p[j]; }
    }
  }
  __syncthreads();
  if (tid == 0) rowptr[N_NODES] = scarry;
}

__global__ void k_fill(const int* __restrict__ dst, int* __restrict__ wp, int* __restrict__ csr){
  int i = blockIdx.x * blockDim.x + threadIdx.x;
  if (i < N_EDGES){
    int p = atomicAdd(&wp[dst[i]], 1);
    csr[p] = i;
  }
}

// ---------------- QKV: [M,128] @ 3x [128,128] -> bf16 outputs (mode-1 weights -> vector stores) ----------------
__global__ __launch_bounds__(512) void k_qkv(
    const float* __restrict__ v, const char* __restrict__ img,
    bf16_t* __restrict__ Q, bf16_t* __restrict__ K, bf16_t* __restrict__ V, int M)
{
  __shared__ __align__(16) char sm[65536];
  char* sX = sm;
  char* sW = sm + 32768;
  const int tid = threadIdx.x, lane = tid & 63, wave = tid >> 6;
  const int r0 = blockIdx.x * 128;
  for (int c = tid; c < 2048; c += 512){
    int row = c >> 4, kc = c & 15, grow = r0 + row;
    float f[8];
    if (grow < M){
      const float4* p = (const float4*)(v + (size_t)grow * DIM + kc * 8);
      float4 u0 = p[0], u1 = p[1];
      f[0]=u0.x; f[1]=u0.y; f[2]=u0.z; f[3]=u0.w;
      f[4]=u1.x; f[5]=u1.y; f[6]=u1.z; f[7]=u1.w;
    } else {
#pragma unroll
      for (int j=0;j<8;j++) f[j] = 0.f;
    }
    bf16x8 o;
#pragma unroll
    for (int j=0;j<8;j++) o[j] = (bf16_t)f[j];
    *(bf16x8*)(sX + row * 256 + swz(row, kc * 16)) = o;
  }
  const int rowA = wave * 16 + (lane & 15);
  const int kb0 = (lane >> 4) * 16;
  const int crow = wave*16 + (lane >> 4)*4;
  const int ccol = lane & 15;
  const f32x4 zero4 = {0.f, 0.f, 0.f, 0.f};
#pragma unroll
  for (int w3 = 0; w3 < 3; w3++){
    __syncthreads();            // staging done / prev GEMM done with sW
    copy16(sW, img + w3 * 32768, 32768);
    __syncthreads();
    f32x4 acc[8];
#pragma unroll
    for (int b=0;b<8;b++) acc[b] = zero4;
#pragma unroll
    for (int ks=0; ks<4; ks++){
      bf16x8 a = lds_frag(sX, rowA, 256, ks*64 + kb0);
#pragma unroll
      for (int nt=0; nt<8; nt++){
        int rn = nt*16 + (lane & 15);
        bf16x8 b = lds_frag(sW, rn, 256, ks*64 + kb0);
        acc[nt] = MFMA(a, b, acc[nt]);
      }
    }
    bf16_t* o = (w3 == 0) ? Q : ((w3 == 1) ? K : V);
    // mode-1 perm: acc[nt] = logical col ccol*8+nt -> one bf16x8 store per row
#pragma unroll
    for (int r=0; r<4; r++){
      int grow = r0 + crow + r;
      if (grow < M){
        bf16x8 t;
#pragma unroll
        for (int nt=0; nt<8; nt++) t[nt] = (bf16_t)acc[nt][r];
        *(bf16x8*)(o + (size_t)grow * DIM + ccol*8) = t;
      }
    }
  }
}

// ---------------- fused edge attention ----------------
// Direct-global A-frags for e; e1_pre written as bf16 row-local (stride RSTRIDE).
__global__ __launch_bounds__(512, 4) void k_edge(
    const float* __restrict__ e,
    const int* __restrict__ src, const int* __restrict__ dst,
    const bf16_t* __restrict__ Qb, const bf16_t* __restrict__ Kb,
    const char* __restrict__ imgWe, const char* __restrict__ imgWo,
    const float* __restrict__ bOe,
    bf16_t* __restrict__ e1_pre, float* __restrict__ sv,
    float* __restrict__ stats, int M)
{
  __shared__ __align__(16) char sm[66560];
  char* sW = sm;                          // 32KB: We then WO_e
  char* sX = sm + 32768;                  // 32KB: score
  float* sStats = (float*)(sm + 65536);   // 256 f
  const int tid = threadIdx.x, lane = tid & 63, wave = tid >> 6;
  const int r0 = blockIdx.x * 128;
  const int crow = wave*16 + (lane >> 4)*4;
  const int ccol = lane & 15;
  const int rowA = wave * 16 + (lane & 15);
  const int q = lane >> 4;
  const int kb0 = q * 16;
  // prefetch K[src]/Q[dst] fragments (in flight through We copy + conversion)
  bf16x8 Kg[4], Qg[4];
#pragma unroll
  for (int r=0;r<4;r++){
    int ed = r0 + crow + r; if (ed >= M) ed = M - 1;
    int sn = src[ed], dn = dst[ed];
    Kg[r] = *(const bf16x8*)(Kb + (size_t)sn * DIM + ccol * 8);
    Qg[r] = *(const bf16x8*)(Qb + (size_t)dn * DIM + ccol * 8);
  }
  // direct A: e row rowA fragments (clamped; garbage rows are epilogue-guarded)
  int grA = r0 + rowA; if (grA >= M) grA = M - 1;
  const f32x4* epA = (const f32x4*)(e + (size_t)grA * DIM);
  f32x4 ea[8];
#pragma unroll
  for (int ks=0; ks<4; ks++){
    ea[2*ks]   = epA[ks*8 + q*2];
    ea[2*ks+1] = epA[ks*8 + q*2 + 1];
  }
  copy16(sW, imgWe, 32768);
  if (tid < 256) sStats[tid] = 0.f;
  bf16x8 eAb[4];
#pragma unroll
  for (int ks=0; ks<4; ks++){
#pragma unroll
    for (int j=0;j<4;j++){
      eAb[ks][j]   = (bf16_t)ea[2*ks][j];
      eAb[ks][4+j] = (bf16_t)ea[2*ks+1][j];
    }
  }
  __syncthreads();   // B1: We staged
  const f32x4 zero4 = {0.f,0.f,0.f,0.f};
  // issue WO loads (land during GEMM1)
  f32x4 wbuf[4];
#pragma unroll
  for (int i=0;i<4;i++) wbuf[i] = *(const f32x4*)(imgWo + tid*16 + i*8192);
  f32x4 pe[8];
#pragma unroll
  for (int i=0;i<8;i++) pe[i] = zero4;
#pragma unroll
  for (int ks=0; ks<4; ks++){
#pragma unroll
    for (int nt=0; nt<8; nt++){
      int rn = nt*16 + (lane & 15);
      bf16x8 b = lds_frag(sW, rn, 256, ks*64 + kb0);
      pe[nt] = MFMA(eAb[ks], b, pe[nt]);
    }
  }
  __syncthreads();   // B2: all waves done reading We
  // write WO_e into sW (reg-staged); issue f32 residual loads (L2-warm tile lines)
#pragma unroll
  for (int i=0;i<4;i++) *(f32x4*)(sW + tid*16 + i*8192) = wbuf[i];
  f32x4 er[8];
#pragma unroll
  for (int r=0;r<4;r++){
    int gr = r0 + crow + r; if (gr >= M) gr = M - 1;
    const f32x4* rp = (const f32x4*)(e + (size_t)gr*DIM + ccol*8);
    er[2*r]   = rp[0];
    er[2*r+1] = rp[1];
  }
  // score: logical col ccol*8+nt -> one bf16x8 per row into sX
#pragma unroll
  for (int r=0;r<4;r++){
    int row = crow + r;
    bf16x8 t;
    float hsum = 0.f;
#pragma unroll
    for (int nt=0; nt<8; nt++){
      float sc = pe[nt][r] * 0.25f * (float)Kg[r][nt] * (float)Qg[r][nt];
      t[nt] = (bf16_t)sc;
      hsum += sc;
    }
    *(bf16x8*)(sX + row*256 + swz(row, ccol*16)) = t;
    float ts = hsum + __shfl_xor(hsum, 1);   // pair covers the full 16-col head
    int ed = r0 + row;
    if (!(ccol & 1) && ed < M)
      sv[(size_t)ed*8 + (ccol >> 1)] = __expf(fminf(5.f, fmaxf(-5.f, ts)));
  }
  __syncthreads();   // B3: score + WO ready
  // GEMM2: e_attn @ WO_e
  f32x4 a2[8];
#pragma unroll
  for (int i=0;i<8;i++) a2[i] = zero4;
#pragma unroll
  for (int ks=0; ks<4; ks++){
    bf16x8 a = lds_frag(sX, rowA, 256, ks*64 + kb0);
#pragma unroll
    for (int nt=0; nt<8; nt++){
      int rn = nt*16 + (lane & 15);
      bf16x8 b = lds_frag(sW, rn, 256, ks*64 + kb0);
      a2[nt] = MFMA(a, b, a2[nt]);
    }
  }
  // epilogue: f32 residual from regs, bf16 row-local store
  float4 bo0 = *(const float4*)(bOe + ccol*8);
  float4 bo1 = *(const float4*)(bOe + ccol*8 + 4);
  float s1[8], s2[8];
#pragma unroll
  for (int j=0;j<8;j++){ s1[j]=0.f; s2[j]=0.f; }
#pragma unroll
  for (int r=0; r<4; r++){
    int ed = r0 + crow + r;
    float val[8];
    if (ed < M){
      val[0]=a2[0][r]+er[2*r][0]+bo0.x; val[1]=a2[1][r]+er[2*r][1]+bo0.y;
      val[2]=a2[2][r]+er[2*r][2]+bo0.z; val[3]=a2[3][r]+er[2*r][3]+bo0.w;
      val[4]=a2[4][r]+er[2*r+1][0]+bo1.x; val[5]=a2[5][r]+er[2*r+1][1]+bo1.y;
      val[6]=a2[6][r]+er[2*r+1][2]+bo1.z; val[7]=a2[7][r]+er[2*r+1][3]+bo1.w;
      bf16x8 t;
#pragma unroll
      for (int j=0;j<8;j++) t[j] = (bf16_t)val[j];
      *(bf16x8*)(e1_pre + (size_t)ed*RSTRIDE + ccol*8) = t;
    } else {
#pragma unroll
      for (int j=0;j<8;j++) val[j]=0.f;
    }
#pragma unroll
    for (int j=0;j<8;j++){ s1[j] += val[j]; s2[j] += val[j]*val[j]; }
  }
#pragma unroll
  for (int j=0;j<8;j++){
    s1[j] += __shfl_xor(s1[j], 16); s1[j] += __shfl_xor(s1[j], 32);
    s2[j] += __shfl_xor(s2[j], 16); s2[j] += __shfl_xor(s2[j], 32);
  }
  if (lane < 16){
#pragma unroll
    for (int j=0;j<8;j++){
      atomicAdd(&sStats[ccol*8 + j], s1[j]);
      atomicAdd(&sStats[128 + ccol*8 + j], s2[j]);
    }
  }
  __syncthreads();
  if (tid < 256) unsafeAtomicAdd(&stats[tid], sStats[tid]);
}

// ---------------- aggregation: one wave per node, CSR walk, 4-deep pipelined ----------------
__global__ __launch_bounds__(512) void k_agg(
    const int* __restrict__ rowptr, const int* __restrict__ csr,
    const int* __restrict__ src, const float* __restrict__ envl,
    const float* __restrict__ sv, const bf16_t* __restrict__ V,
    bf16_t* __restrict__ vAttn, int M)
{
  const int wave = threadIdx.x >> 6, lane = threadIdx.x & 63;
  const int n = blockIdx.x * 8 + wave;
  if (n >= M) return;
  const int beg = rowptr[n], end = rowptr[n + 1];
  const int h = lane >> 3;           // head of cols (2*lane, 2*lane+1)
  float ax = 0.f, ay = 0.f, zacc = 0.f;
  int i = beg;
  for (; i + 4 <= end; i += 4){
    int e0 = csr[i], e1 = csr[i+1], e2 = csr[i+2], e3 = csr[i+3];
    int sn0 = src[e0], sn1 = src[e1], sn2 = src[e2], sn3 = src[e3];
    float sv0 = sv[(size_t)e0*8 + h], sv1 = sv[(size_t)e1*8 + h];
    float sv2 = sv[(size_t)e2*8 + h], sv3 = sv[(size_t)e3*8 + h];
    float n0 = envl[e0], n1 = envl[e1], n2 = envl[e2], n3 = envl[e3];
    bf16x2 a0 = *(const bf16x2*)(V + (size_t)sn0 * DIM + lane * 2);
    bf16x2 a1 = *(const bf16x2*)(V + (size_t)sn1 * DIM + lane * 2);
    bf16x2 a2v = *(const bf16x2*)(V + (size_t)sn2 * DIM + lane * 2);
    bf16x2 a3 = *(const bf16x2*)(V + (size_t)sn3 * DIM + lane * 2);
    float w0 = n0*sv0, w1 = n1*sv1, w2 = n2*sv2, w3 = n3*sv3;
    ax += (float)a0[0]*w0 + (float)a1[0]*w1 + (float)a2v[0]*w2 + (float)a3[0]*w3;
    ay += (float)a0[1]*w0 + (float)a1[1]*w1 + (float)a2v[1]*w2 + (float)a3[1]*w3;
    zacc += sv0 + sv1 + sv2 + sv3;
  }
  for (; i < end; i++){
    int eid = csr[i];
    int sn = src[eid];
    float s = sv[(size_t)eid * 8 + h];
    float env = envl[eid];
    const bf16x2 vv = *(const bf16x2*)(V + (size_t)sn * DIM + lane * 2);
    float w = env * s;
    ax += (float)vv[0] * w; ay += (float)vv[1] * w;
    zacc += s;
  }
  float inv = 1.f / (zacc + 1e-6f);
  bf16x2 o; o[0] = (bf16_t)(ax * inv); o[1] = (bf16_t)(ay * inv);
  *(bf16x2*)(vAttn + (size_t)n * DIM + lane * 2) = o;
}

// ---------------- node: v1_pre = v + v_attn@WO_v + bOv; bf16 row-local; stats ----------------
__global__ __launch_bounds__(512) void k_nodeout(
    const bf16_t* __restrict__ vAttn, const float* __restrict__ v,
    const char* __restrict__ imgWo, const float* __restrict__ bOv,
    bf16_t* __restrict__ v1_pre, float* __restrict__ stats, int M)
{
  __shared__ __align__(16) char sm[66560];
  char* sW = sm;
  char* sX = sm + 32768;
  float* sStats = (float*)(sm + 65536);
  const int tid = threadIdx.x, lane = tid & 63, wave = tid >> 6;
  const int r0 = blockIdx.x * 128;
  copy16(sW, imgWo, 32768);
  if (tid < 256) sStats[tid] = 0.f;
  for (int c = tid; c < 2048; c += 512){
    int row = c >> 4, kc = c & 15, grow = r0 + row;
    bf16x8 o;
    if (grow < M){
      o = *(const bf16x8*)(vAttn + (size_t)grow * DIM + kc * 8);
    } else {
#pragma unroll
      for (int j=0;j<8;j++) o[j] = (bf16_t)0.f;
    }
    *(bf16x8*)(sX + row*256 + swz(row, kc*16)) = o;
  }
  __syncthreads();
  const int rowA = wave*16 + (lane & 15);
  const int kb0 = (lane >> 4)*16;
  const f32x4 zero4 = {0.f,0.f,0.f,0.f};
  f32x4 acc[8];
#pragma unroll
  for (int i=0;i<8;i++) acc[i]=zero4;
#pragma unroll
  for (int ks=0;ks<4;ks++){
    bf16x8 a = lds_frag(sX, rowA, 256, ks*64+kb0);
#pragma unroll
    for (int nt=0;nt<8;nt++){
      int rn = nt*16 + (lane&15);
      bf16x8 b = lds_frag(sW, rn, 256, ks*64+kb0);
      acc[nt] = MFMA(a,b,acc[nt]);
    }
  }
  const int crow = wave*16 + (lane>>4)*4;
  const int ccol = lane & 15;
  float4 bo0 = *(const float4*)(bOv + ccol*8);
  float4 bo1 = *(const float4*)(bOv + ccol*8 + 4);
  float s1[8], s2[8];
#pragma unroll
  for (int j=0;j<8;j++){ s1[j]=0.f; s2[j]=0.f; }
#pragma unroll
  for (int r=0;r<4;r++){
    int grow = r0 + crow + r;
    float val[8];
    if (grow < M){
      const float4* vp = (const float4*)(v + (size_t)grow*DIM + ccol*8);
      float4 v0 = vp[0], v1 = vp[1];
      val[0]=acc[0][r]+v0.x+bo0.x; val[1]=acc[1][r]+v0.y+bo0.y;
      val[2]=acc[2][r]+v0.z+bo0.z; val[3]=acc[3][r]+v0.w+bo0.w;
      val[4]=acc[4][r]+v1.x+bo1.x; val[5]=acc[5][r]+v1.y+bo1.y;
      val[6]=acc[6][r]+v1.z+bo1.z; val[7]=acc[7][r]+v1.w+bo1.w;
      bf16x8 t;
#pragma unroll
      for (int j=0;j<8;j++) t[j] = (bf16_t)val[j];
      *(bf16x8*)(v1_pre + (size_t)grow*RSTRIDE + ccol*8) = t;
    } else {
#pragma unroll
      for (int j=0;j<8;j++) val[j]=0.f;
    }
#pragma unroll
    for (int j=0;j<8;j++){ s1[j] += val[j]; s2[j] += val[j]*val[j]; }
  }
#pragma unroll
  for (int j=0;j<8;j++){
    s1[j] += __shfl_xor(s1[j], 16); s1[j] += __shfl_xor(s1[j], 32);
    s2[j] += __shfl_xor(s2[j], 16); s2[j] += __shfl_xor(s2[j], 32);
  }
  if (lane < 16){
#pragma unroll
    for (int j=0;j<8;j++){
      atomicAdd(&sStats[ccol*8 + j], s1[j]);
      atomicAdd(&sStats[128 + ccol*8 + j], s2[j]);
    }
  }
  __syncthreads();
  if (tid < 256) unsafeAtomicAdd(&stats[tid], sStats[tid]);
}

// ---------------- fused FFN ----------------
// xio is bf16 row-local (stride RSTRIDE). Direct-global bf16 A-frags with inline BN;
// sA holds only h (hswz); W1 mode-3, W2 mode-1; writes x2_pre bf16 row-local in place.
__global__ __launch_bounds__(512, 4) void k_ffn(
    bf16_t* __restrict__ xio, const float* __restrict__ ss1,
    const char* __restrict__ img1, const float* __restrict__ b1,
    const char* __restrict__ img2, const float* __restrict__ b2,
    float* __restrict__ stats2, int M)
{
  __shared__ __align__(16) char sm[66560];
  char* sA = sm;           // h halves (hswz layout)
  char* sB = sm + 32768;   // W1h0, W1h1, W2k0, W2k1
  float* sStats = (float*)(sm + 65536);
  const int tid = threadIdx.x, lane = tid & 63, wave = tid >> 6;
  const int r0 = blockIdx.x * 128;
  const int rowA = wave*16 + (lane & 15);
  const int q = lane >> 4;
  const int kb0 = q * 16;
  const int crow = wave*16 + q*4;
  const int ccol = lane & 15;
  const f32x4 zero4 = {0.f,0.f,0.f,0.f};

  // BN scale/shift for this thread's 8 contiguous epilogue cols
  float4 sc0 = *(const float4*)(ss1 + ccol*8);
  float4 sc1 = *(const float4*)(ss1 + ccol*8 + 4);
  float4 sh0 = *(const float4*)(ss1 + 128 + ccol*8);
  float4 sh1 = *(const float4*)(ss1 + 128 + ccol*8 + 4);
  // biases for this thread's 16 contiguous logical hcols
  const float4* bq = (const float4*)(b1 + ccol * 16);
  float4 bq0 = bq[0], bq1 = bq[1], bq2 = bq[2], bq3 = bq[3];

  // phase 1: W1h0 -> LDS; direct bf16 A row-frag loads + BN; footprint residual
  copy16(sB, img1, 32768);
  if (tid < 256) sStats[tid] = 0.f;
  int grA = r0 + rowA; if (grA >= M) grA = M - 1;
  const bf16_t* xrow = xio + (size_t)grA * RSTRIDE;
  bf16x8 araw[4];
#pragma unroll
  for (int ks=0; ks<4; ks++)
    araw[ks] = *(const bf16x8*)(xrow + ks*32 + q*8);
  bf16x8 xres[4];
#pragma unroll
  for (int r = 0; r < 4; r++){
    int grow = r0 + crow + r;
    bf16x8 o;
    if (grow < M){
      bf16x8 u = *(const bf16x8*)(xio + (size_t)grow*RSTRIDE + ccol*8);
      o[0]=(bf16_t)((float)u[0]*sc0.x+sh0.x); o[1]=(bf16_t)((float)u[1]*sc0.y+sh0.y);
      o[2]=(bf16_t)((float)u[2]*sc0.z+sh0.z); o[3]=(bf16_t)((float)u[3]*sc0.w+sh0.w);
      o[4]=(bf16_t)((float)u[4]*sc1.x+sh1.x); o[5]=(bf16_t)((float)u[5]*sc1.y+sh1.y);
      o[6]=(bf16_t)((float)u[6]*sc1.z+sh1.z); o[7]=(bf16_t)((float)u[7]*sc1.w+sh1.w);
    } else {
#pragma unroll
      for (int j=0;j<8;j++) o[j]=(bf16_t)0.f;
    }
    xres[r] = o;
  }
  // BN on A frags (ss is L1-resident)
  bf16x8 xAb[4];
#pragma unroll
  for (int ks=0; ks<4; ks++){
    const f32x4* sp = (const f32x4*)(ss1 + ks*32 + q*8);
    const f32x4* hp = (const f32x4*)(ss1 + 128 + ks*32 + q*8);
    f32x4 s0 = sp[0], s1v = sp[1], h0 = hp[0], h1 = hp[1];
#pragma unroll
    for (int j=0;j<4;j++){
      xAb[ks][j]   = (bf16_t)((float)araw[ks][j]  *s0[j]  + h0[j]);
      xAb[ks][4+j] = (bf16_t)((float)araw[ks][4+j]*s1v[j] + h1[j]);
    }
  }
  __syncthreads();  // B1: W1h0 ready

  bf16x8 hreg[8];   // [r] = half0 hcols (nt 0..7), [4+r] = half1 (nt 8..15)
  f32x4 wbuf[4];    // reg-staged next weight chunk

  // phase 2: GEMM1a (+ issue W1 half1 loads)
#pragma unroll
  for (int i=0;i<4;i++) wbuf[i] = *(const f32x4*)(img1 + 32768 + tid*16 + i*8192);
  {
    f32x4 acc[8];
#pragma unroll
    for (int i=0;i<8;i++) acc[i]=zero4;
#pragma unroll
    for (int ks=0;ks<4;ks++){
#pragma unroll
      for (int nt=0;nt<8;nt++){
        int rn = nt*16 + (lane&15);
        bf16x8 b = lds_frag(sB, rn, 256, ks*64+kb0);
        acc[nt] = MFMA(xAb[ks], b, acc[nt]);
      }
    }
#pragma unroll
    for (int r=0;r<4;r++){
      bf16x8 t;
      t[0]=(bf16_t)fmaxf(acc[0][r]+bq0.x,0.f); t[1]=(bf16_t)fmaxf(acc[1][r]+bq0.y,0.f);
      t[2]=(bf16_t)fmaxf(acc[2][r]+bq0.z,0.f); t[3]=(bf16_t)fmaxf(acc[3][r]+bq0.w,0.f);
      t[4]=(bf16_t)fmaxf(acc[4][r]+bq1.x,0.f); t[5]=(bf16_t)fmaxf(acc[5][r]+bq1.y,0.f);
      t[6]=(bf16_t)fmaxf(acc[6][r]+bq1.z,0.f); t[7]=(bf16_t)fmaxf(acc[7][r]+bq1.w,0.f);
      hreg[r] = t;
    }
  }
  __syncthreads();
  // phase 3: write W1 half1
#pragma unroll
  for (int i=0;i<4;i++) *(f32x4*)(sB + tid*16 + i*8192) = wbuf[i];
  __syncthreads();
  // phase 4: GEMM1b (+ issue W2 k-half0 loads)
#pragma unroll
  for (int i=0;i<4;i++){
    int o = tid*16 + i*8192;
    wbuf[i] = *(const f32x4*)(img2 + (o >> 8)*512 + (o & 255));
  }
  {
    f32x4 acc[8];
#pragma unroll
    for (int i=0;i<8;i++) acc[i]=zero4;
#pragma unroll
    for (int ks=0;ks<4;ks++){
#pragma unroll
      for (int nt=0;nt<8;nt++){
        int rn = nt*16 + (lane&15);
        bf16x8 b = lds_frag(sB, rn, 256, ks*64+kb0);
        acc[nt] = MFMA(xAb[ks], b, acc[nt]);
      }
    }
#pragma unroll
    for (int r=0;r<4;r++){
      bf16x8 t;
      t[0]=(bf16_t)fmaxf(acc[0][r]+bq2.x,0.f); t[1]=(bf16_t)fmaxf(acc[1][r]+bq2.y,0.f);
      t[2]=(bf16_t)fmaxf(acc[2][r]+bq2.z,0.f); t[3]=(bf16_t)fmaxf(acc[3][r]+bq2.w,0.f);
      t[4]=(bf16_t)fmaxf(acc[4][r]+bq3.x,0.f); t[5]=(bf16_t)fmaxf(acc[5][r]+bq3.y,0.f);
      t[6]=(bf16_t)fmaxf(acc[6][r]+bq3.z,0.f); t[7]=(bf16_t)fmaxf(acc[7][r]+bq3.w,0.f);
      hreg[4+r] = t;
    }
  }
  __syncthreads();   // sB free

  f32x4 o2[8];
#pragma unroll
  for (int i=0;i<8;i++) o2[i]=zero4;

#pragma unroll
  for (int half = 0; half < 2; half++){
    // write h k-half into sA (hswz layout, rows 256B of 128 hcols)
    if ((ccol >> 3) == half){
      int cb = (ccol & 7) * 32;
#pragma unroll
      for (int r=0;r<4;r++){
        int row = crow + r;
        *(bf16x8*)(sA + row*256 + hswz(row, cb))      = hreg[r];
        *(bf16x8*)(sA + row*256 + hswz(row, cb + 16)) = hreg[4+r];
      }
    }
    // write W2 k-half (reg-staged)
#pragma unroll
    for (int i=0;i<4;i++) *(f32x4*)(sB + tid*16 + i*8192) = wbuf[i];
    __syncthreads();
    // issue loads for W2 k-half1 during GEMM2a
    if (half == 0){
#pragma unroll
      for (int i=0;i<4;i++){
        int o = tid*16 + i*8192;
        wbuf[i] = *(const f32x4*)(img2 + (o >> 8)*512 + 256 + (o & 255));
      }
    }
    // GEMM2 over this k-half
#pragma unroll
    for (int ks=0;ks<4;ks++){
      const char* ap = sA + rowA*256 + hswz(rowA, ks*64+kb0);
      bf16x8 a = *(const bf16x8*)ap;
#pragma unroll
      for (int nt=0;nt<8;nt++){
        int rn = nt*16 + (lane&15);
        bf16x8 b = lds_frag(sB, rn, 256, ks*64+kb0);
        o2[nt] = MFMA(a,b,o2[nt]);
      }
    }
    __syncthreads();
  }

  // epilogue: residual from regs (x1 bf16), bf16 row-local in-place store
  float4 b20 = *(const float4*)(b2 + ccol*8);
  float4 b21 = *(const float4*)(b2 + ccol*8 + 4);
  float s1[8], s2[8];
#pragma unroll
  for (int j=0;j<8;j++){ s1[j]=0.f; s2[j]=0.f; }
#pragma unroll
  for (int r=0;r<4;r++){
    int grow = r0 + crow + r;
    float val[8];
    val[0]=(float)xres[r][0]+o2[0][r]+b20.x; val[1]=(float)xres[r][1]+o2[1][r]+b20.y;
    val[2]=(float)xres[r][2]+o2[2][r]+b20.z; val[3]=(float)xres[r][3]+o2[3][r]+b20.w;
    val[4]=(float)xres[r][4]+o2[4][r]+b21.x; val[5]=(float)xres[r][5]+o2[5][r]+b21.y;
    val[6]=(float)xres[r][6]+o2[6][r]+b21.z; val[7]=(float)xres[r][7]+o2[7][r]+b21.w;
    if (grow < M){
      bf16x8 t;
#pragma unroll
      for (int j=0;j<8;j++) t[j] = (bf16_t)val[j];
      *(bf16x8*)(xio + (size_t)grow*RSTRIDE + ccol*8) = t;
    } else {
#pragma unroll
      for (int j=0;j<8;j++) val[j]=0.f;
    }
#pragma unroll
    for (int j=0;j<8;j++){ s1[j] += val[j]; s2[j] += val[j]*val[j]; }
  }
#pragma unroll
  for (int j=0;j<8;j++){
    s1[j] += __shfl_xor(s1[j], 16); s1[j] += __shfl_xor(s1[j], 32);
    s2[j] += __shfl_xor(s2[j], 16); s2[j] += __shfl_xor(s2[j], 32);
  }
  if (lane < 16){
#pragma unroll
    for (int j=0;j<8;j++){
      atomicAdd(&sStats[ccol*8 + j], s1[j]);
      atomicAdd(&sStats[128 + ccol*8 + j], s2[j]);
    }
  }
  __syncthreads();
  if (tid < 256) unsafeAtomicAdd(&stats2[tid], sStats[tid]);
}

// ---------------- stats -> scale/shift ----------------
struct FinArgs { const float* st; const float* g; const float* b; float* ss; float invM; };

__global__ void k_finstats(FinArgs a0, FinArgs a1){
  FinArgs a = (blockIdx.x == 0) ? a0 : a1;
  int c = threadIdx.x;
  float mean = a.st[c] * a.invM;
  float var  = a.st[128 + c] * a.invM - mean * mean;
  float scl  = a.g[c] * rsqrtf(var + 1e-5f);
  a.ss[c] = scl;
  a.ss[128 + c] = a.b[c] - mean * scl;
}

// ---------------- in-place bf16->f32 normalize-expand (race-free per row) ----------------
// Row i: bf16 source in first 256B of its 512B slot; 16 consecutive lanes (one wave) own
// the row; the wave-wide load completes (vmcnt) before any lane's dependent store issues.
__global__ __launch_bounds__(256) void k_norm2(
    char* __restrict__ xv, char* __restrict__ xe,
    const float* __restrict__ ssv, const float* __restrict__ sse,
    long long nv, long long ne)
{
  long long tv = nv * 16, total = tv + ne * 16;
  for (long long g = (long long)blockIdx.x * blockDim.x + threadIdx.x; g < total;
       g += (long long)gridDim.x * blockDim.x){
    bool isv = g < tv;
    char* base = isv ? xv : xe;
    const float* ss = isv ? ssv : sse;
    long long gg = isv ? g : g - tv;
    long long row = gg >> 4;
    int c = (int)(gg & 15);
    bf16x8 u = *(const bf16x8*)(base + row * 512 + c * 16);
    int c0 = c * 8;
    float4 o0, o1;
    o0.x = (float)u[0]*ss[c0+0] + ss[128+c0+0];
    o0.y = (float)u[1]*ss[c0+1] + ss[128+c0+1];
    o0.z = (float)u[2]*ss[c0+2] + ss[128+c0+2];
    o0.w = (float)u[3]*ss[c0+3] + ss[128+c0+3];
    o1.x = (float)u[4]*ss[c0+4] + ss[128+c0+4];
    o1.y = (float)u[5]*ss[c0+5] + ss[128+c0+5];
    o1.z = (float)u[6]*ss[c0+6] + ss[128+c0+6];
    o1.w = (float)u[7]*ss[c0+7] + ss[128+c0+7];
    float4* dp = (float4*)(base + row * 512 + c * 32);
    dp[0] = o0; dp[1] = o1;
  }
}

extern "C" void kernel_launch(void* const* d_in, const int* in_sizes, int n_in,
                              void* d_out, int out_size, void* d_ws, size_t ws_size,
                              hipStream_t stream)
{
  const float* v    = (const float*)d_in[0];
  const float* e    = (const float*)d_in[1];
  const float* envl = (const float*)d_in[2];
  const int*   src  = (const int*)d_in[3];
  const int*   dst  = (const int*)d_in[4];
  const float* bOv  = (const float*)d_in[10];
  const float* bOe  = (const float*)d_in[12];
  const float* g1v  = (const float*)d_in[13];
  const float* b1vn = (const float*)d_in[14];
  const float* g1e  = (const float*)d_in[15];
  const float* b1en = (const float*)d_in[16];
  const float* g2v  = (const float*)d_in[17];
  const float* b2vn = (const float*)d_in[18];
  const float* g2e  = (const float*)d_in[19];
  const float* b2en = (const float*)d_in[20];
  const float* b1vf = (const float*)d_in[22];
  const float* b2vf = (const float*)d_in[24];
  const float* b1ef = (const float*)d_in[26];
  const float* b2ef = (const float*)d_in[28];

  float* out_v = (float*)d_out;
  float* out_e = out_v + (size_t)N_NODES * DIM;
  bf16_t* v1b = (bf16_t*)out_v;   // bf16 row-local view (stride RSTRIDE elems)
  bf16_t* e1b = (bf16_t*)out_e;

  char* ws = (char*)d_ws;
  const size_t IMG_OFF = 0;                        // 458752 B of bf16 weight images
  const size_t QB_OFF  = 458752;                   // bf16 Q  (N*128*2 = 12.8MB)
  const size_t KB_OFF  = QB_OFF  + 12800000;       // bf16 K
  const size_t VB_OFF  = KB_OFF  + 12800000;       // bf16 V
  const size_t VA_OFF  = VB_OFF  + 12800000;       // bf16 vAttn
  const size_t SV_OFF  = VA_OFF  + 12800000;       // s per edge per head: E*8*4 = 16MB
  const size_t CSR_OFF = SV_OFF  + 16000000;       // E ints
  const size_t RP_OFF  = CSR_OFF + 2000000;        // N+1 ints
  const size_t WP_OFF  = RP_OFF  + 200016;         // N ints
  const size_t CNT_OFF = WP_OFF  + 200000;         // N ints (memset 0)
  const size_t ST_OFF  = CNT_OFF + 200000;         // 1024 f (memset 0)
  const size_t SS_OFF  = ST_OFF  + 4096;           // 1024 f

  char*   img   = ws + IMG_OFF;
  bf16_t* Qb    = (bf16_t*)(ws + QB_OFF);
  bf16_t* Kb    = (bf16_t*)(ws + KB_OFF);
  bf16_t* Vb    = (bf16_t*)(ws + VB_OFF);
  bf16_t* vAttn = (bf16_t*)(ws + VA_OFF);
  float*  svp   = (float*)(ws + SV_OFF);
  int*    csr   = (int*)(ws + CSR_OFF);
  int*    rowp  = (int*)(ws + RP_OFF);
  int*    wpp   = (int*)(ws + WP_OFF);
  int*    cnt   = (int*)(ws + CNT_OFF);
  float*  st    = (float*)(ws + ST_OFF);
  float*  ssb   = (float*)(ws + SS_OFF);
  float* st_e1 = st;        float* st_v1 = st + 256;
  float* st_v2 = st + 512;  float* st_e2 = st + 768;
  float* ss_v1 = ssb;       float* ss_e1 = ssb + 256;
  float* ss_v2 = ssb + 512; float* ss_e2 = ssb + 768;

  // zero counters + stats (contiguous)
  (void)hipMemsetAsync(ws + CNT_OFF, 0, 200000 + 4096, stream);

  WPrep wp;
  const int wid[10]   = {5,6,7,8,9,11,21,23,25,27};
  const int Ks[10]    = {128,128,128,128,128,128,128,256,128,256};
  const int Ns[10]    = {128,128,128,128,128,128,256,128,256,128};
  const int modes[10] = {1,1,1,1,1,1,3,1,3,1};   // QKV/We/WO_*/W2: p8 n-perm; W1: p16 n-perm
  int cum = 0, off = 0;
  for (int i = 0; i < 10; i++){
    wp.w[i] = (const float*)d_in[wid[i]];
    wp.Kd[i] = Ks[i]; wp.Nd[i] = Ns[i];
    wp.off[i] = off; wp.cum[i] = cum; wp.mode[i] = modes[i];
    off += Ks[i]*Ns[i]*2; cum += Ks[i]*Ns[i];
  }
  k_wprep<<<896, 256, 0, stream>>>(wp, img, cum);

  // CSR build (independent of QKV)
  k_count<<<1954, 256, 0, stream>>>(dst, cnt);
  k_scan<<<1, 1024, 0, stream>>>(cnt, rowp, wpp);
  k_fill<<<1954, 256, 0, stream>>>(dst, wpp, csr);

  k_qkv<<<391, 512, 0, stream>>>(v, img, Qb, Kb, Vb, N_NODES);

  k_edge<<<3907, 512, 0, stream>>>(e, src, dst, Qb, Kb,
                                   img + 98304 /*We*/, img + 163840 /*WO_e*/, bOe,
                                   e1b, svp, st_e1, N_EDGES);

  k_agg<<<6250, 512, 0, stream>>>(rowp, csr, src, envl, svp, Vb, vAttn, N_NODES);

  k_nodeout<<<391, 512, 0, stream>>>(vAttn, v, img + 131072 /*WO_v*/, bOv,
                                     v1b, st_v1, N_NODES);

  {
    FinArgs fv{st_v1, g1v, b1vn, ss_v1, 1.f / N_NODES};
    FinArgs fe{st_e1, g1e, b1en, ss_e1, 1.f / N_EDGES};
    k_finstats<<<2, 128, 0, stream>>>(fv, fe);
  }

  k_ffn<<<391, 512, 0, stream>>>(v1b, ss_v1, img + 196608 /*W1v*/, b1vf,
                                 img + 262144 /*W2v*/, b2vf, st_v2, N_NODES);
  k_ffn<<<3907, 512, 0, stream>>>(e1b, ss_e1, img + 327680 /*W1e*/, b1ef,
                                  img + 393216 /*W2e*/, b2ef, st_e2, N_EDGES);

  {
    FinArgs fv{st_v2, g2v, b2vn, ss_v2, 1.f / N_NODES};
    FinArgs fe{st_e2, g2e, b2en, ss_e2, 1.f / N_EDGES};
    k_finstats<<<2, 128, 0, stream>>>(fv, fe);
  }

  k_norm2<<<4096, 256, 0, stream>>>((char*)out_v, (char*)out_e, ss_v2, ss_e2,
                                    (long long)N_NODES, (long long)N_EDGES);
}